// Round 10
// baseline (901.142 us; speedup 1.0000x reference)
//
#include <hip/hip_runtime.h>
#include <stdint.h>
#include <stddef.h>

// RWKV-v4 block, MI355X. B=8 T=2048 E=H=1024, fp32 in/out.
// R10 GEMM "gemmBD": 256x256 tile, 8 waves; A staged via global_load_lds into
// 64KB double-buffered LDS (XOR-swizzled); B read DIRECT global->VGPR
// (L1/L2-resident weights, async to barriers); 1 barrier + counted vmcnt/tile.
// wkv: 3-pass chunked scan. Peak ws: 154 MB.
#define Bb 8
#define Tt 2048
#define Ee 1024
#define Hh 1024
#define ROWS (Bb * Tt)   // 16384
#define CC 32            // wkv chunks
#define LL 64            // steps per chunk

typedef __attribute__((ext_vector_type(8))) _Float16 half8v;
typedef __attribute__((ext_vector_type(4))) _Float16 half4v;
typedef __attribute__((ext_vector_type(4))) float f32x4;

#define GL2LDS(gp, lp)                                                        \
  __builtin_amdgcn_global_load_lds(                                          \
      (const __attribute__((address_space(1))) void*)(gp),                   \
      (__attribute__((address_space(3))) void*)(lp), 16, 0, 0)

// compiler-visible waitcnt: vmcnt=n, expcnt=7 (no wait), lgkmcnt=15 (no wait)
#define VMCNT(n) __builtin_amdgcn_s_waitcnt(0xF70 | (n))
#define BAR __builtin_amdgcn_s_barrier()
#define SCHED0 __builtin_amdgcn_sched_barrier(0)

// ---------------- weight convert + transpose: W (KxN f32) -> Wt (NxK f16) --
__global__ __launch_bounds__(256)
void wtrans_kernel(const float* __restrict__ W, _Float16* __restrict__ Wt,
                   const int K, const int N) {
  __shared__ float tle[64][65];
  const int ntn = N >> 6;
  const int tn = blockIdx.x % ntn;
  const int tk = blockIdx.x / ntn;
  const int tid = threadIdx.x;
  const int r = tid >> 4;
  const int c4 = (tid & 15) * 4;
#pragma unroll
  for (int i = 0; i < 4; i++) {
    const int row = r + i * 16;
    const float4 v = *reinterpret_cast<const float4*>(
        &W[(size_t)(tk * 64 + row) * N + tn * 64 + c4]);
    tle[row][c4] = v.x; tle[row][c4 + 1] = v.y;
    tle[row][c4 + 2] = v.z; tle[row][c4 + 3] = v.w;
  }
  __syncthreads();
#pragma unroll
  for (int j = 0; j < 2; j++) {
    const int ch = tid + j * 256;
    const int n = ch >> 3;
    const int k8 = (ch & 7) * 8;
    half8v o;
#pragma unroll
    for (int m = 0; m < 8; m++) o[m] = (_Float16)tle[k8 + m][n];
    *reinterpret_cast<half8v*>(&Wt[(size_t)(tn * 64 + n) * K + tk * 64 + k8]) = o;
  }
}

// ---------------- LayerNorm: one wave per row of 1024, f16 output ----------
__global__ __launch_bounds__(256)
void ln_kernel(const float* __restrict__ x, const float* __restrict__ gw,
               const float* __restrict__ bw, _Float16* __restrict__ h) {
  const int row = blockIdx.x * 4 + (threadIdx.x >> 6);
  const int lane = threadIdx.x & 63;
  const float4* xr = reinterpret_cast<const float4*>(x + (size_t)row * Ee);
  float4 v[4];
  float s = 0.f, sq = 0.f;
#pragma unroll
  for (int i = 0; i < 4; i++) {
    v[i] = xr[lane + i * 64];
    s += v[i].x + v[i].y + v[i].z + v[i].w;
    sq += v[i].x * v[i].x + v[i].y * v[i].y + v[i].z * v[i].z + v[i].w * v[i].w;
  }
#pragma unroll
  for (int o = 32; o > 0; o >>= 1) {
    s += __shfl_xor(s, o);
    sq += __shfl_xor(sq, o);
  }
  const float mu = s * (1.f / Ee);
  const float var = sq * (1.f / Ee) - mu * mu;
  const float rs = rsqrtf(var + 1e-3f);
  const float4* gr = reinterpret_cast<const float4*>(gw);
  const float4* br = reinterpret_cast<const float4*>(bw);
#pragma unroll
  for (int i = 0; i < 4; i++) {
    const int c = lane + i * 64;
    const float4 g4 = gr[c], b4 = br[c];
    half4v o;
    o[0] = (_Float16)((v[i].x - mu) * rs * g4.x + b4.x);
    o[1] = (_Float16)((v[i].y - mu) * rs * g4.y + b4.y);
    o[2] = (_Float16)((v[i].z - mu) * rs * g4.z + b4.z);
    o[3] = (_Float16)((v[i].w - mu) * rs * g4.w + b4.w);
    *reinterpret_cast<half4v*>(&h[(size_t)row * Ee + (size_t)c * 4]) = o;
  }
}

// ---------------- time-shift mix: xk/xv/xr = h*m + h[t-1]*(1-m) ------------
template <bool HASV>
__global__ __launch_bounds__(256)
void mix_kernel(const _Float16* __restrict__ h, const float* __restrict__ mk,
                const float* __restrict__ mv, const float* __restrict__ mr,
                _Float16* __restrict__ xk, _Float16* __restrict__ xv,
                _Float16* __restrict__ xr) {
  const int gid = blockIdx.x * 256 + threadIdx.x;
  const int row = gid >> 8;
  const int c = gid & 255;
  const int t = row & (Tt - 1);
  const size_t o = (size_t)row * 1024 + (size_t)c * 4;
  const half4v hv4 = *reinterpret_cast<const half4v*>(&h[o]);
  float hx[4] = {(float)hv4[0], (float)hv4[1], (float)hv4[2], (float)hv4[3]};
  float h1[4] = {0.f, 0.f, 0.f, 0.f};
  if (t > 0) {
    const half4v p4 = *reinterpret_cast<const half4v*>(&h[o - 1024]);
    h1[0] = (float)p4[0]; h1[1] = (float)p4[1];
    h1[2] = (float)p4[2]; h1[3] = (float)p4[3];
  }
  const float4 k4 = reinterpret_cast<const float4*>(mk)[c];
  const float4 r4 = reinterpret_cast<const float4*>(mr)[c];
  const float km[4] = {k4.x, k4.y, k4.z, k4.w};
  const float rm[4] = {r4.x, r4.y, r4.z, r4.w};
  half4v ok, orr;
#pragma unroll
  for (int j = 0; j < 4; j++) {
    ok[j] = (_Float16)(hx[j] * km[j] + h1[j] * (1.f - km[j]));
    orr[j] = (_Float16)(hx[j] * rm[j] + h1[j] * (1.f - rm[j]));
  }
  *reinterpret_cast<half4v*>(&xk[o]) = ok;
  *reinterpret_cast<half4v*>(&xr[o]) = orr;
  if constexpr (HASV) {
    const float4 v4 = reinterpret_cast<const float4*>(mv)[c];
    const float vm[4] = {v4.x, v4.y, v4.z, v4.w};
    half4v ov;
#pragma unroll
    for (int j = 0; j < 4; j++)
      ov[j] = (_Float16)(hx[j] * vm[j] + h1[j] * (1.f - vm[j]));
    *reinterpret_cast<half4v*>(&xv[o]) = ov;
  }
}

// ---------------- WKV chunked scan -----------------------------------------
__global__ __launch_bounds__(256)
void wkv_pass1(const _Float16* __restrict__ kb, const _Float16* __restrict__ vb,
               const float* __restrict__ decay,
               float* __restrict__ aal, float* __restrict__ bbl,
               float* __restrict__ ppl) {
  const int gid = blockIdx.x * 256 + threadIdx.x;  // B*CC*H
  const int h = gid & 1023;
  const int rest = gid >> 10;
  const int c = rest & (CC - 1);
  const int b = rest >> 5;
  const float w = -__expf(decay[h]);
  const size_t base = ((size_t)b * Tt + (size_t)c * LL) * Hh + h;
  float aa = 0.f, bb = 0.f, pp = -1e38f;
  for (int i0 = 0; i0 < LL; i0 += 8) {
    float kt[8], vt[8];
#pragma unroll
    for (int j = 0; j < 8; j++) {
      const size_t idx = base + (size_t)(i0 + j) * Hh;
      kt[j] = (float)kb[idx];
      vt[j] = (float)vb[idx];
    }
#pragma unroll
    for (int j = 0; j < 8; j++) {
      const float ww2 = pp + w;
      const float q2 = fmaxf(ww2, kt[j]);
      const float e1 = __expf(ww2 - q2);
      const float e2 = __expf(kt[j] - q2);
      aa = e1 * aa + e2 * vt[j];
      bb = e1 * bb + e2;
      pp = q2;
    }
  }
  const int sidx = (b * CC + c) * Hh + h;
  aal[sidx] = aa; bbl[sidx] = bb; ppl[sidx] = pp;
}

__global__ __launch_bounds__(256)
void wkv_pass2(const float* __restrict__ decay,
               const float* __restrict__ aal, const float* __restrict__ bbl,
               const float* __restrict__ ppl,
               float* __restrict__ aap, float* __restrict__ bbp,
               float* __restrict__ ppp) {
  const int gid = blockIdx.x * 256 + threadIdx.x;  // B*H
  const int h = gid & 1023;
  const int b = gid >> 10;
  const float w = -__expf(decay[h]);
  const float Lw = (float)LL * w;
  float aa = 0.f, bb = 0.f, pp = -1e38f;
#pragma unroll
  for (int c = 0; c < CC; c++) {
    const int sidx = (b * CC + c) * Hh + h;
    aap[sidx] = aa; bbp[sidx] = bb; ppp[sidx] = pp;
    const float la = aal[sidx], lb = bbl[sidx], lp = ppl[sidx];
    const float sp = pp + Lw;
    const float q = fmaxf(sp, lp);
    const float e1 = __expf(sp - q);
    const float e2 = __expf(lp - q);
    aa = e1 * aa + e2 * la;
    bb = e1 * bb + e2 * lb;
    pp = q;
  }
}

__global__ __launch_bounds__(256)
void wkv_pass3(const _Float16* __restrict__ kb, const _Float16* __restrict__ vb,
               const _Float16* __restrict__ rb,
               const float* __restrict__ decay, const float* __restrict__ first,
               const float* __restrict__ aap, const float* __restrict__ bbp,
               const float* __restrict__ ppp, _Float16* __restrict__ ab) {
  const int gid = blockIdx.x * 256 + threadIdx.x;  // B*CC*H
  const int h = gid & 1023;
  const int rest = gid >> 10;
  const int c = rest & (CC - 1);
  const int b = rest >> 5;
  const float w = -__expf(decay[h]);
  const float u = first[h];
  const int sidx = (b * CC + c) * Hh + h;
  float aa = aap[sidx], bb = bbp[sidx], pp = ppp[sidx];
  const size_t base = ((size_t)b * Tt + (size_t)c * LL) * Hh + h;
  for (int i0 = 0; i0 < LL; i0 += 8) {
    float kt[8], vt[8], rr[8];
#pragma unroll
    for (int j = 0; j < 8; j++) {
      const size_t idx = base + (size_t)(i0 + j) * Hh;
      kt[j] = (float)kb[idx];
      vt[j] = (float)vb[idx];
      rr[j] = (float)rb[idx];
    }
#pragma unroll
    for (int j = 0; j < 8; j++) {
      const float ww = u + kt[j];
      const float q = fmaxf(pp, ww);
      const float e1 = __expf(pp - q);
      const float e2 = __expf(ww - q);
      const float out = (e1 * aa + e2 * vt[j]) / (e1 * bb + e2);
      const float sr = 1.f / (1.f + __expf(-rr[j]));
      ab[base + (size_t)(i0 + j) * Hh] = (_Float16)(sr * out);
      const float ww2 = pp + w;
      const float q2 = fmaxf(ww2, kt[j]);
      const float e1b = __expf(ww2 - q2);
      const float e2b = __expf(kt[j] - q2);
      aa = e1b * aa + e2b * vt[j];
      bb = e1b * bb + e2b;
      pp = q2;
    }
  }
}

// ---------------- gemmBD: C = A(MxK) * Bt(NxK)^T, f16 ----------------------
// 256x256 tile, 8 waves (2M x 4N), per-wave 128x64 output (acc[8][4]).
// A: global_load_lds -> 64KB double-buffered LDS, XOR-swizzled 16B slots.
// B: DIRECT global->VGPR (weights are L1/L2-resident), double-buffered in
//    registers, async to the barrier (vmcnt-tracked per-use by compiler).
// Per K-tile: { stageA(t+1) | ds_read a(t) | 64 MFMA (a x bC) |
//               loadB(t+1)->bN | VMCNT(8) [drains A(t+1) only] | BAR | bC=bN }
// EPI: 0 f16; 1 relu^2 f16; 2 sigmoid f16; 3 f32 res+val; 4 f32 += scale*val
template <int EPI>
__global__ __launch_bounds__(512)
void gemmBD(const _Float16* __restrict__ A, const int ldA,
            const _Float16* __restrict__ Bt, const int ldB,
            const int N, const int K, const int nbx,
            float* __restrict__ outF, _Float16* __restrict__ outH,
            const float* __restrict__ res, const _Float16* __restrict__ scale) {
  extern __shared__ _Float16 sA[];   // [2][256*64] f16 = 64 KB
  const int tid = threadIdx.x;
  const int lane = tid & 63;
  const int w = tid >> 6;
  const int wm = w >> 2, wn = w & 3;           // 2 M-groups x 4 N-groups
  const int r0 = lane & 15, kg = lane >> 4;
  // bijective XCD swizzle (gridDim.x % 8 == 0)
  const int cpx = gridDim.x >> 3;
  const int wg = ((int)blockIdx.x & 7) * cpx + ((int)blockIdx.x >> 3);
  const int bm = (wg / nbx) * 256;
  const int bn = (wg % nbx) * 256;
  const int NT = K >> 6;

  f32x4 acc[8][4];
#pragma unroll
  for (int i = 0; i < 8; i++)
#pragma unroll
    for (int j = 0; j < 4; j++) acc[i][j] = (f32x4){0.f, 0.f, 0.f, 0.f};

  // stage full A K-tile (256x64 = 32KB): 4 issues/wave x 8 waves.
  // LDS dest linear; source col pre-swizzled: LDS[row][s] = G[row][s^(row&7)]
  auto stageA = [&](int t, int p) {
#pragma unroll
    for (int i = 0; i < 4; i++) {
      const int chunk = w * 4 + i;             // wave-uniform, 0..31
      const int row = chunk * 8 + (lane >> 3);
      const int gs = (lane & 7) ^ (row & 7);
      GL2LDS(A + (size_t)(bm + row) * ldA + (size_t)t * 64 + gs * 8,
             sA + p * 16384 + chunk * 512);
    }
  };
  auto loadB = [&](int t, half8v (&b)[4][2]) {
#pragma unroll
    for (int fc = 0; fc < 4; fc++)
#pragma unroll
      for (int kk = 0; kk < 2; kk++)
        b[fc][kk] = *reinterpret_cast<const half8v*>(
            Bt + (size_t)(bn + wn * 64 + fc * 16 + r0) * ldB +
            (size_t)t * 64 + (size_t)(kk * 4 + kg) * 8);
  };

  half8v bC[4][2], bN[4][2];

  // prologue: A(0) -> buf0, drain; b(0) direct (compiler waits at first use)
  stageA(0, 0);
  VMCNT(0);
  loadB(0, bC);
  BAR;

  for (int t = 0; t < NT; ++t) {
    const int p = t & 1;
    if (t + 1 < NT) stageA(t + 1, p ^ 1);
    SCHED0;
    half8v af[8][2];
#pragma unroll
    for (int fr = 0; fr < 8; fr++)
#pragma unroll
      for (int kk = 0; kk < 2; kk++) {
        const int row = wm * 128 + fr * 16 + r0;
        af[fr][kk] = *reinterpret_cast<const half8v*>(
            sA + p * 16384 + row * 64 + (((kk * 4 + kg) ^ (row & 7)) << 3));
      }
    __builtin_amdgcn_s_setprio(1);
#pragma unroll
    for (int fr = 0; fr < 8; fr++)
#pragma unroll
      for (int fc = 0; fc < 4; fc++)
#pragma unroll
        for (int kk = 0; kk < 2; kk++)
          acc[fr][fc] = __builtin_amdgcn_mfma_f32_16x16x32_f16(
              af[fr][kk], bC[fc][kk], acc[fr][fc], 0, 0, 0);
    __builtin_amdgcn_s_setprio(0);
    SCHED0;
    if (t + 1 < NT) {
      loadB(t + 1, bN);   // newest 8 VMEM ops -> survive VMCNT(8)
      VMCNT(8);           // drains A(t+1) staging (older), keeps bN in flight
    } else {
      VMCNT(0);
    }
    BAR;
#pragma unroll
    for (int fc = 0; fc < 4; fc++)
#pragma unroll
      for (int kk = 0; kk < 2; kk++) bC[fc][kk] = bN[fc][kk];
  }

  // epilogue
#pragma unroll
  for (int fr = 0; fr < 8; fr++) {
#pragma unroll
    for (int fc = 0; fc < 4; fc++) {
#pragma unroll
      for (int i = 0; i < 4; i++) {
        const int row = bm + wm * 128 + fr * 16 + (lane >> 4) * 4 + i;
        const int col = bn + wn * 64 + fc * 16 + r0;
        const size_t idx = (size_t)row * N + col;
        const float val = acc[fr][fc][i];
        if constexpr (EPI == 0) {
          outH[idx] = (_Float16)val;
        } else if constexpr (EPI == 1) {
          const float tt = fmaxf(val, 0.f);
          outH[idx] = (_Float16)(tt * tt);
        } else if constexpr (EPI == 2) {
          outH[idx] = (_Float16)(1.f / (1.f + __expf(-val)));
        } else if constexpr (EPI == 3) {
          outF[idx] = res[idx] + val;
        } else {
          outF[idx] = outF[idx] + (float)scale[idx] * val;
        }
      }
    }
  }
}

// ---------------------------------------------------------------------------
extern "C" void kernel_launch(void* const* d_in, const int* in_sizes, int n_in,
                              void* d_out, int out_size, void* d_ws,
                              size_t ws_size, hipStream_t stream) {
  (void)in_sizes; (void)n_in; (void)out_size; (void)ws_size;
  const float* x_in      = (const float*)d_in[0];
  const float* ln1_g     = (const float*)d_in[1];
  const float* ln1_b     = (const float*)d_in[2];
  const float* ln2_g     = (const float*)d_in[3];
  const float* ln2_b     = (const float*)d_in[4];
  const float* tm_mix_k  = (const float*)d_in[5];
  const float* tm_mix_v  = (const float*)d_in[6];
  const float* tm_mix_r  = (const float*)d_in[7];
  const float* tm_Wk     = (const float*)d_in[8];
  const float* tm_Wv     = (const float*)d_in[9];
  const float* tm_Wr     = (const float*)d_in[10];
  const float* time_decay= (const float*)d_in[11];
  const float* time_first= (const float*)d_in[12];
  const float* Wo        = (const float*)d_in[13];
  const float* cm_mix_k  = (const float*)d_in[14];
  const float* cm_mix_r  = (const float*)d_in[15];
  const float* cm_Wk     = (const float*)d_in[16];
  const float* cm_Wv     = (const float*)d_in[17];
  const float* cm_Wr     = (const float*)d_in[18];
  float* out = (float*)d_out;
  char* ws = (char*)d_ws;
  const size_t MB = 1024ull * 1024ull;

  // ---- workspace layout, peak 154 MB ----
  _Float16* WkT   = (_Float16*)(ws + 0 * MB);    // 2MB (1024x1024 f16)
  _Float16* WvT   = (_Float16*)(ws + 2 * MB);
  _Float16* WrT   = (_Float16*)(ws + 4 * MB);
  _Float16* WoT   = (_Float16*)(ws + 6 * MB);
  _Float16* cmWkT = (_Float16*)(ws + 8 * MB);    // 8MB (4096x1024)
  _Float16* cmWvT = (_Float16*)(ws + 16 * MB);   // 8MB (1024x4096)
  _Float16* cmWrT = (_Float16*)(ws + 24 * MB);   // 2MB
  // wkv scratch reuses WkT/WvT/WrT slots (dead after k/v/r GEMMs):
  float* aal = (float*)(ws + 0 * MB);            // 1MB each
  float* bbl = (float*)(ws + 1 * MB);
  float* ppl = (float*)(ws + 2 * MB);
  float* aap = (float*)(ws + 3 * MB);
  float* bbp = (float*)(ws + 4 * MB);
  float* ppp = (float*)(ws + 5 * MB);
  // time-mix slots (32MB each):
  _Float16* h16   = (_Float16*)(ws + 26 * MB);   // [26,58)
  _Float16* xk    = (_Float16*)(ws + 58 * MB);   // [58,90)
  _Float16* xv    = (_Float16*)(ws + 90 * MB);   // [90,122)
  _Float16* xr    = (_Float16*)(ws + 122 * MB);  // [122,154)
  _Float16* kb    = h16;
  _Float16* vb    = xk;
  _Float16* rb    = xv;
  _Float16* ab    = xr;
  // channel-mix (full 16384 rows, K-split of the 4096 dim):
  _Float16* h2    = (_Float16*)(ws + 26 * MB);   // [26,58)  dead before kc
  _Float16* xr2   = (_Float16*)(ws + 58 * MB);   // [58,90)  dead before kc
  _Float16* xk2   = (_Float16*)(ws + 90 * MB);   // [90,122)
  _Float16* rc    = (_Float16*)(ws + 122 * MB);  // [122,154)
  _Float16* kc    = (_Float16*)(ws + 26 * MB);   // [26,90) 64MB (16384x2048)

  const int SMEM = 65536;
  static bool attr_done = false;
  if (!attr_done) {
    hipFuncSetAttribute((const void*)gemmBD<0>, hipFuncAttributeMaxDynamicSharedMemorySize, SMEM);
    hipFuncSetAttribute((const void*)gemmBD<1>, hipFuncAttributeMaxDynamicSharedMemorySize, SMEM);
    hipFuncSetAttribute((const void*)gemmBD<2>, hipFuncAttributeMaxDynamicSharedMemorySize, SMEM);
    hipFuncSetAttribute((const void*)gemmBD<3>, hipFuncAttributeMaxDynamicSharedMemorySize, SMEM);
    hipFuncSetAttribute((const void*)gemmBD<4>, hipFuncAttributeMaxDynamicSharedMemorySize, SMEM);
    attr_done = true;
  }

  // --- weight prep ---
  wtrans_kernel<<<dim3(256), 256, 0, stream>>>(tm_Wk, WkT, 1024, 1024);
  wtrans_kernel<<<dim3(256), 256, 0, stream>>>(tm_Wv, WvT, 1024, 1024);
  wtrans_kernel<<<dim3(256), 256, 0, stream>>>(tm_Wr, WrT, 1024, 1024);
  wtrans_kernel<<<dim3(256), 256, 0, stream>>>(Wo, WoT, 1024, 1024);
  wtrans_kernel<<<dim3(1024), 256, 0, stream>>>(cm_Wk, cmWkT, 1024, 4096);
  wtrans_kernel<<<dim3(1024), 256, 0, stream>>>(cm_Wv, cmWvT, 4096, 1024);
  wtrans_kernel<<<dim3(256), 256, 0, stream>>>(cm_Wr, cmWrT, 1024, 1024);

  // --- time mixing ---
  ln_kernel<<<dim3(ROWS / 4), 256, 0, stream>>>(x_in, ln1_g, ln1_b, h16);
  mix_kernel<true><<<dim3(ROWS), 256, 0, stream>>>(h16, tm_mix_k, tm_mix_v,
                                                   tm_mix_r, xk, xv, xr);
  gemmBD<0><<<dim3(64 * 4), 512, SMEM, stream>>>(xk, 1024, WkT, 1024, 1024,
                                                 1024, 4, nullptr, kb, nullptr,
                                                 nullptr);
  gemmBD<0><<<dim3(64 * 4), 512, SMEM, stream>>>(xv, 1024, WvT, 1024, 1024,
                                                 1024, 4, nullptr, vb, nullptr,
                                                 nullptr);
  gemmBD<0><<<dim3(64 * 4), 512, SMEM, stream>>>(xr, 1024, WrT, 1024, 1024,
                                                 1024, 4, nullptr, rb, nullptr,
                                                 nullptr);
  wkv_pass1<<<dim3(Bb * CC * Hh / 256), 256, 0, stream>>>(kb, vb, time_decay,
                                                          aal, bbl, ppl);
  wkv_pass2<<<dim3(Bb * Hh / 256), 256, 0, stream>>>(time_decay, aal, bbl, ppl,
                                                     aap, bbp, ppp);
  wkv_pass3<<<dim3(Bb * CC * Hh / 256), 256, 0, stream>>>(
      kb, vb, rb, time_decay, time_first, aap, bbp, ppp, ab);
  gemmBD<3><<<dim3(64 * 4), 512, SMEM, stream>>>(ab, 1024, WoT, 1024, 1024,
                                                 1024, 4, out, nullptr, x_in,
                                                 nullptr);

  // --- channel mixing (full rows, 2 K-halves of the 4096 dim) ---
  ln_kernel<<<dim3(ROWS / 4), 256, 0, stream>>>(out, ln2_g, ln2_b, h2);
  mix_kernel<false><<<dim3(ROWS), 256, 0, stream>>>(h2, cm_mix_k, nullptr,
                                                    cm_mix_r, xk2, nullptr, xr2);
  gemmBD<2><<<dim3(64 * 4), 512, SMEM, stream>>>(xr2, 1024, cmWrT, 1024, 1024,
                                                 1024, 4, nullptr, rc, nullptr,
                                                 nullptr);
  for (int half = 0; half < 2; half++) {
    const _Float16* Bk = cmWkT + (size_t)half * 2048 * 1024;  // rows of N-half
    const _Float16* Bv = cmWvT + (size_t)half * 2048;         // K-half cols
    gemmBD<1><<<dim3(64 * 8), 512, SMEM, stream>>>(xk2, 1024, Bk, 1024, 2048,
                                                   1024, 8, nullptr, kc,
                                                   nullptr, nullptr);
    gemmBD<4><<<dim3(64 * 4), 512, SMEM, stream>>>(kc, 2048, Bv, 4096, 1024,
                                                   2048, 4, out, nullptr,
                                                   nullptr, rc);
  }
}

// Round 11
// 706.115 us; speedup vs baseline: 1.2762x; 1.2762x over previous
//
#include <hip/hip_runtime.h>
#include <stdint.h>
#include <stddef.h>

// RWKV-v4 block, MI355X. B=8 T=2048 E=H=1024, fp32 in/out.
// R11: GEMM = R9 2-phase 256x256 (best measured, 722-726 us family).
//      NEW: fused LN+time-shift-mix (lnmix) — h intermediate eliminated;
//      each wave computes LN(row) and LN(row-1) in registers.
// wkv: 3-pass chunked scan. Peak ws: 154 MB.
#define Bb 8
#define Tt 2048
#define Ee 1024
#define Hh 1024
#define ROWS (Bb * Tt)   // 16384
#define CC 32            // wkv chunks
#define LL 64            // steps per chunk

typedef __attribute__((ext_vector_type(8))) _Float16 half8v;
typedef __attribute__((ext_vector_type(4))) _Float16 half4v;
typedef __attribute__((ext_vector_type(4))) float f32x4;

#define GL2LDS(gp, lp)                                                        \
  __builtin_amdgcn_global_load_lds(                                          \
      (const __attribute__((address_space(1))) void*)(gp),                   \
      (__attribute__((address_space(3))) void*)(lp), 16, 0, 0)

// compiler-visible waitcnt: vmcnt=n, expcnt=7 (no wait), lgkmcnt=15 (no wait)
#define VMCNT(n) __builtin_amdgcn_s_waitcnt(0xF70 | (n))
#define BAR __builtin_amdgcn_s_barrier()
#define SCHED0 __builtin_amdgcn_sched_barrier(0)

// ---------------- weight convert + transpose: W (KxN f32) -> Wt (NxK f16) --
__global__ __launch_bounds__(256)
void wtrans_kernel(const float* __restrict__ W, _Float16* __restrict__ Wt,
                   const int K, const int N) {
  __shared__ float tle[64][65];
  const int ntn = N >> 6;
  const int tn = blockIdx.x % ntn;
  const int tk = blockIdx.x / ntn;
  const int tid = threadIdx.x;
  const int r = tid >> 4;
  const int c4 = (tid & 15) * 4;
#pragma unroll
  for (int i = 0; i < 4; i++) {
    const int row = r + i * 16;
    const float4 v = *reinterpret_cast<const float4*>(
        &W[(size_t)(tk * 64 + row) * N + tn * 64 + c4]);
    tle[row][c4] = v.x; tle[row][c4 + 1] = v.y;
    tle[row][c4 + 2] = v.z; tle[row][c4 + 3] = v.w;
  }
  __syncthreads();
#pragma unroll
  for (int j = 0; j < 2; j++) {
    const int ch = tid + j * 256;
    const int n = ch >> 3;
    const int k8 = (ch & 7) * 8;
    half8v o;
#pragma unroll
    for (int m = 0; m < 8; m++) o[m] = (_Float16)tle[k8 + m][n];
    *reinterpret_cast<half8v*>(&Wt[(size_t)(tn * 64 + n) * K + tk * 64 + k8]) = o;
  }
}

// ------- fused LayerNorm + time-shift mix: one wave per output row ---------
// h  = LN(x[row]); h1 = (t>0) ? LN(x[row-1]) : 0   (zero-pad, matches ref)
// xk = h*mk + h1*(1-mk); xr = h*mr + h1*(1-mr); [xv likewise if HASV]
template <bool HASV>
__global__ __launch_bounds__(256)
void lnmix_kernel(const float* __restrict__ x, const float* __restrict__ gw,
                  const float* __restrict__ bw,
                  const float* __restrict__ mk, const float* __restrict__ mv,
                  const float* __restrict__ mr,
                  _Float16* __restrict__ xk, _Float16* __restrict__ xv,
                  _Float16* __restrict__ xr) {
  const int row = blockIdx.x * 4 + (threadIdx.x >> 6);
  const int lane = threadIdx.x & 63;
  const int t = row & (Tt - 1);
  const bool hasprev = (t > 0);          // wave-uniform
  const float4* xc = reinterpret_cast<const float4*>(x + (size_t)row * Ee);
  const float4* xp = reinterpret_cast<const float4*>(x + (size_t)(row - 1) * Ee);
  float4 v[4], pv[4];
  float s = 0.f, sq = 0.f, s1 = 0.f, sq1 = 0.f;
#pragma unroll
  for (int i = 0; i < 4; i++) {
    v[i] = xc[lane + i * 64];
    s += v[i].x + v[i].y + v[i].z + v[i].w;
    sq += v[i].x * v[i].x + v[i].y * v[i].y + v[i].z * v[i].z + v[i].w * v[i].w;
    if (hasprev) {
      pv[i] = xp[lane + i * 64];
      s1 += pv[i].x + pv[i].y + pv[i].z + pv[i].w;
      sq1 += pv[i].x * pv[i].x + pv[i].y * pv[i].y + pv[i].z * pv[i].z +
             pv[i].w * pv[i].w;
    } else {
      pv[i] = (float4){0.f, 0.f, 0.f, 0.f};
    }
  }
#pragma unroll
  for (int o = 32; o > 0; o >>= 1) {
    s += __shfl_xor(s, o);
    sq += __shfl_xor(sq, o);
    s1 += __shfl_xor(s1, o);
    sq1 += __shfl_xor(sq1, o);
  }
  const float mu = s * (1.f / Ee);
  const float rs = rsqrtf(sq * (1.f / Ee) - mu * mu + 1e-3f);
  const float mu1 = s1 * (1.f / Ee);
  const float rs1 = hasprev ? rsqrtf(sq1 * (1.f / Ee) - mu1 * mu1 + 1e-3f) : 0.f;
  const float4* gr = reinterpret_cast<const float4*>(gw);
  const float4* br = reinterpret_cast<const float4*>(bw);
#pragma unroll
  for (int i = 0; i < 4; i++) {
    const int c = lane + i * 64;
    const float4 g4 = gr[c], b4 = br[c];
    float h[4], h1[4];
    h[0] = (v[i].x - mu) * rs * g4.x + b4.x;
    h[1] = (v[i].y - mu) * rs * g4.y + b4.y;
    h[2] = (v[i].z - mu) * rs * g4.z + b4.z;
    h[3] = (v[i].w - mu) * rs * g4.w + b4.w;
    if (hasprev) {
      h1[0] = (pv[i].x - mu1) * rs1 * g4.x + b4.x;
      h1[1] = (pv[i].y - mu1) * rs1 * g4.y + b4.y;
      h1[2] = (pv[i].z - mu1) * rs1 * g4.z + b4.z;
      h1[3] = (pv[i].w - mu1) * rs1 * g4.w + b4.w;
    } else {
      h1[0] = h1[1] = h1[2] = h1[3] = 0.f;   // ZeroPadding1D semantics
    }
    const float4 k4 = reinterpret_cast<const float4*>(mk)[c];
    const float4 r4 = reinterpret_cast<const float4*>(mr)[c];
    const float km[4] = {k4.x, k4.y, k4.z, k4.w};
    const float rm[4] = {r4.x, r4.y, r4.z, r4.w};
    const size_t o = (size_t)row * Ee + (size_t)c * 4;
    half4v ok, orr;
#pragma unroll
    for (int j = 0; j < 4; j++) {
      ok[j] = (_Float16)(h[j] * km[j] + h1[j] * (1.f - km[j]));
      orr[j] = (_Float16)(h[j] * rm[j] + h1[j] * (1.f - rm[j]));
    }
    *reinterpret_cast<half4v*>(&xk[o]) = ok;
    *reinterpret_cast<half4v*>(&xr[o]) = orr;
    if constexpr (HASV) {
      const float4 v4 = reinterpret_cast<const float4*>(mv)[c];
      const float vm[4] = {v4.x, v4.y, v4.z, v4.w};
      half4v ov;
#pragma unroll
      for (int j = 0; j < 4; j++)
        ov[j] = (_Float16)(h[j] * vm[j] + h1[j] * (1.f - vm[j]));
      *reinterpret_cast<half4v*>(&xv[o]) = ov;
    }
  }
}

// ---------------- WKV chunked scan -----------------------------------------
__global__ __launch_bounds__(256)
void wkv_pass1(const _Float16* __restrict__ kb, const _Float16* __restrict__ vb,
               const float* __restrict__ decay,
               float* __restrict__ aal, float* __restrict__ bbl,
               float* __restrict__ ppl) {
  const int gid = blockIdx.x * 256 + threadIdx.x;  // B*CC*H
  const int h = gid & 1023;
  const int rest = gid >> 10;
  const int c = rest & (CC - 1);
  const int b = rest >> 5;
  const float w = -__expf(decay[h]);
  const size_t base = ((size_t)b * Tt + (size_t)c * LL) * Hh + h;
  float aa = 0.f, bb = 0.f, pp = -1e38f;
  for (int i0 = 0; i0 < LL; i0 += 8) {
    float kt[8], vt[8];
#pragma unroll
    for (int j = 0; j < 8; j++) {
      const size_t idx = base + (size_t)(i0 + j) * Hh;
      kt[j] = (float)kb[idx];
      vt[j] = (float)vb[idx];
    }
#pragma unroll
    for (int j = 0; j < 8; j++) {
      const float ww2 = pp + w;
      const float q2 = fmaxf(ww2, kt[j]);
      const float e1 = __expf(ww2 - q2);
      const float e2 = __expf(kt[j] - q2);
      aa = e1 * aa + e2 * vt[j];
      bb = e1 * bb + e2;
      pp = q2;
    }
  }
  const int sidx = (b * CC + c) * Hh + h;
  aal[sidx] = aa; bbl[sidx] = bb; ppl[sidx] = pp;
}

__global__ __launch_bounds__(256)
void wkv_pass2(const float* __restrict__ decay,
               const float* __restrict__ aal, const float* __restrict__ bbl,
               const float* __restrict__ ppl,
               float* __restrict__ aap, float* __restrict__ bbp,
               float* __restrict__ ppp) {
  const int gid = blockIdx.x * 256 + threadIdx.x;  // B*H
  const int h = gid & 1023;
  const int b = gid >> 10;
  const float w = -__expf(decay[h]);
  const float Lw = (float)LL * w;
  float aa = 0.f, bb = 0.f, pp = -1e38f;
#pragma unroll
  for (int c = 0; c < CC; c++) {
    const int sidx = (b * CC + c) * Hh + h;
    aap[sidx] = aa; bbp[sidx] = bb; ppp[sidx] = pp;
    const float la = aal[sidx], lb = bbl[sidx], lp = ppl[sidx];
    const float sp = pp + Lw;
    const float q = fmaxf(sp, lp);
    const float e1 = __expf(sp - q);
    const float e2 = __expf(lp - q);
    aa = e1 * aa + e2 * la;
    bb = e1 * bb + e2 * lb;
    pp = q;
  }
}

__global__ __launch_bounds__(256)
void wkv_pass3(const _Float16* __restrict__ kb, const _Float16* __restrict__ vb,
               const _Float16* __restrict__ rb,
               const float* __restrict__ decay, const float* __restrict__ first,
               const float* __restrict__ aap, const float* __restrict__ bbp,
               const float* __restrict__ ppp, _Float16* __restrict__ ab) {
  const int gid = blockIdx.x * 256 + threadIdx.x;  // B*CC*H
  const int h = gid & 1023;
  const int rest = gid >> 10;
  const int c = rest & (CC - 1);
  const int b = rest >> 5;
  const float w = -__expf(decay[h]);
  const float u = first[h];
  const int sidx = (b * CC + c) * Hh + h;
  float aa = aap[sidx], bb = bbp[sidx], pp = ppp[sidx];
  const size_t base = ((size_t)b * Tt + (size_t)c * LL) * Hh + h;
  for (int i0 = 0; i0 < LL; i0 += 8) {
    float kt[8], vt[8], rr[8];
#pragma unroll
    for (int j = 0; j < 8; j++) {
      const size_t idx = base + (size_t)(i0 + j) * Hh;
      kt[j] = (float)kb[idx];
      vt[j] = (float)vb[idx];
      rr[j] = (float)rb[idx];
    }
#pragma unroll
    for (int j = 0; j < 8; j++) {
      const float ww = u + kt[j];
      const float q = fmaxf(pp, ww);
      const float e1 = __expf(pp - q);
      const float e2 = __expf(ww - q);
      const float out = (e1 * aa + e2 * vt[j]) / (e1 * bb + e2);
      const float sr = 1.f / (1.f + __expf(-rr[j]));
      ab[base + (size_t)(i0 + j) * Hh] = (_Float16)(sr * out);
      const float ww2 = pp + w;
      const float q2 = fmaxf(ww2, kt[j]);
      const float e1b = __expf(ww2 - q2);
      const float e2b = __expf(kt[j] - q2);
      aa = e1b * aa + e2b * vt[j];
      bb = e1b * bb + e2b;
      pp = q2;
    }
  }
}

// ---------------- 256x256 2-phase GEMM: C = A(MxK) * Bt(NxK)^T, f16 --------
// (R9 form — best measured. XOR-swizzled LDS, counted vmcnt, 4 barriers/tile.)
// EPI: 0 f16; 1 relu^2 f16; 2 sigmoid f16; 3 f32 res+val; 4 f32 += scale*val
template <int EPI>
__global__ __launch_bounds__(512, 2)
void gemm8(const _Float16* __restrict__ A, const int ldA,
           const _Float16* __restrict__ Bt, const int ldB,
           const int N, const int K, const int nbx,
           float* __restrict__ outF, _Float16* __restrict__ outH,
           const float* __restrict__ res, const _Float16* __restrict__ scale) {
  extern __shared__ _Float16 smem[];
  _Float16* sA = smem;               // [2][256*64]
  _Float16* sB = smem + 2 * 16384;   // [2][256*64]
  const int tid = threadIdx.x;
  const int lane = tid & 63;
  const int w = tid >> 6;
  const int wm = w >> 2, wn = w & 3;
  const int r0 = lane & 15, kg = lane >> 4;
  // bijective XCD swizzle (gridDim.x % 8 == 0)
  const int cpx = gridDim.x >> 3;
  const int wg = ((int)blockIdx.x & 7) * cpx + ((int)blockIdx.x >> 3);
  const int bm = (wg / nbx) * 256;
  const int bn = (wg % nbx) * 256;
  const int NT = K >> 6;

  f32x4 acc[8][4];
#pragma unroll
  for (int i = 0; i < 8; i++)
#pragma unroll
    for (int j = 0; j < 4; j++) acc[i][j] = (f32x4){0.f, 0.f, 0.f, 0.f};

  auto stage = [&](const _Float16* __restrict__ G, const int ldG,
                   const int growbase, const int t, _Float16* sX, const int hb) {
    _Float16* base = sX + (t & 1) * 16384 + hb * 8192;
#pragma unroll
    for (int i = 0; i < 2; i++) {
      const int rih = (w * 2 + i) * 8 + (lane >> 3);
      const int gs = (lane & 7) ^ (rih & 7);
      GL2LDS(G + (size_t)(growbase + hb * 128 + rih) * ldG + (size_t)t * 64 + gs * 8,
             base + (w * 2 + i) * 512);
    }
  };
  auto rdA = [&](int p, int row, int ks) -> half8v {
    return *reinterpret_cast<const half8v*>(
        sA + p * 16384 + row * 64 + ((ks ^ (row & 7)) << 3));
  };
  auto rdB = [&](int p, int row, int ks) -> half8v {
    return *reinterpret_cast<const half8v*>(
        sB + p * 16384 + row * 64 + ((ks ^ (row & 7)) << 3));
  };

  // prologue: tile0 (A0,A1,B1,B0) + tile1 (A0,A1); drain tile0, keep A(1)
  stage(A, ldA, bm, 0, sA, 0);
  stage(A, ldA, bm, 0, sA, 1);
  stage(Bt, ldB, bn, 0, sB, 1);
  stage(Bt, ldB, bn, 0, sB, 0);
  if (NT > 1) { stage(A, ldA, bm, 1, sA, 0); stage(A, ldA, bm, 1, sA, 1); }
  VMCNT(4);
  BAR;
  SCHED0;

  for (int t = 0; t < NT; ++t) {
    const int p = t & 1;
    half8v a0[4][2], a1[4][2], b0[2][2], b1[2][2];
    // ---- phase 1: stage B(t+1); read ALL 24 frags; MFMA a0/a1 x b0 ----
    if (t + 1 < NT) {
      stage(Bt, ldB, bn, t + 1, sB, 1);
      stage(Bt, ldB, bn, t + 1, sB, 0);
    }
#pragma unroll
    for (int fr = 0; fr < 4; fr++)
#pragma unroll
      for (int kk = 0; kk < 2; kk++)
        a0[fr][kk] = rdA(p, wm * 128 + fr * 16 + r0, kk * 4 + kg);
#pragma unroll
    for (int fr = 0; fr < 4; fr++)
#pragma unroll
      for (int kk = 0; kk < 2; kk++)
        a1[fr][kk] = rdA(p, wm * 128 + 64 + fr * 16 + r0, kk * 4 + kg);
#pragma unroll
    for (int fc = 0; fc < 2; fc++)
#pragma unroll
      for (int kk = 0; kk < 2; kk++)
        b0[fc][kk] = rdB(p, wn * 64 + fc * 16 + r0, kk * 4 + kg);
#pragma unroll
    for (int fc = 0; fc < 2; fc++)
#pragma unroll
      for (int kk = 0; kk < 2; kk++)
        b1[fc][kk] = rdB(p, wn * 64 + 32 + fc * 16 + r0, kk * 4 + kg);
    BAR;
    __builtin_amdgcn_s_setprio(1);
#pragma unroll
    for (int fr = 0; fr < 4; fr++)
#pragma unroll
      for (int fc = 0; fc < 2; fc++)
#pragma unroll
        for (int kk = 0; kk < 2; kk++)
          acc[fr][fc] = __builtin_amdgcn_mfma_f32_16x16x32_f16(
              a0[fr][kk], b0[fc][kk], acc[fr][fc], 0, 0, 0);
#pragma unroll
    for (int fr = 0; fr < 4; fr++)
#pragma unroll
      for (int fc = 0; fc < 2; fc++)
#pragma unroll
        for (int kk = 0; kk < 2; kk++)
          acc[4 + fr][fc] = __builtin_amdgcn_mfma_f32_16x16x32_f16(
              a1[fr][kk], b0[fc][kk], acc[4 + fr][fc], 0, 0, 0);
    __builtin_amdgcn_s_setprio(0);
    SCHED0;
    BAR;
    // ---- phase 2: stage A(t+2); counted vmcnt; MFMA a1/a0 x b1 ----
    if (t + 2 < NT) {
      stage(A, ldA, bm, t + 2, sA, 0);
      stage(A, ldA, bm, t + 2, sA, 1);
      VMCNT(4);
    } else {
      VMCNT(0);
    }
    BAR;
    __builtin_amdgcn_s_setprio(1);
#pragma unroll
    for (int fr = 0; fr < 4; fr++)
#pragma unroll
      for (int fc = 0; fc < 2; fc++)
#pragma unroll
        for (int kk = 0; kk < 2; kk++)
          acc[4 + fr][2 + fc] = __builtin_amdgcn_mfma_f32_16x16x32_f16(
              a1[fr][kk], b1[fc][kk], acc[4 + fr][2 + fc], 0, 0, 0);
#pragma unroll
    for (int fr = 0; fr < 4; fr++)
#pragma unroll
      for (int fc = 0; fc < 2; fc++)
#pragma unroll
        for (int kk = 0; kk < 2; kk++)
          acc[fr][2 + fc] = __builtin_amdgcn_mfma_f32_16x16x32_f16(
              a0[fr][kk], b1[fc][kk], acc[fr][2 + fc], 0, 0, 0);
    __builtin_amdgcn_s_setprio(0);
    SCHED0;
    BAR;
  }
  VMCNT(0);

  // epilogue
#pragma unroll
  for (int fr = 0; fr < 8; fr++) {
#pragma unroll
    for (int fc = 0; fc < 4; fc++) {
#pragma unroll
      for (int i = 0; i < 4; i++) {
        const int row = bm + wm * 128 + fr * 16 + (lane >> 4) * 4 + i;
        const int col = bn + wn * 64 + fc * 16 + r0;
        const size_t idx = (size_t)row * N + col;
        const float val = acc[fr][fc][i];
        if constexpr (EPI == 0) {
          outH[idx] = (_Float16)val;
        } else if constexpr (EPI == 1) {
          const float tt = fmaxf(val, 0.f);
          outH[idx] = (_Float16)(tt * tt);
        } else if constexpr (EPI == 2) {
          outH[idx] = (_Float16)(1.f / (1.f + __expf(-val)));
        } else if constexpr (EPI == 3) {
          outF[idx] = res[idx] + val;
        } else {
          outF[idx] = outF[idx] + (float)scale[idx] * val;
        }
      }
    }
  }
}

// ---------------------------------------------------------------------------
extern "C" void kernel_launch(void* const* d_in, const int* in_sizes, int n_in,
                              void* d_out, int out_size, void* d_ws,
                              size_t ws_size, hipStream_t stream) {
  (void)in_sizes; (void)n_in; (void)out_size; (void)ws_size;
  const float* x_in      = (const float*)d_in[0];
  const float* ln1_g     = (const float*)d_in[1];
  const float* ln1_b     = (const float*)d_in[2];
  const float* ln2_g     = (const float*)d_in[3];
  const float* ln2_b     = (const float*)d_in[4];
  const float* tm_mix_k  = (const float*)d_in[5];
  const float* tm_mix_v  = (const float*)d_in[6];
  const float* tm_mix_r  = (const float*)d_in[7];
  const float* tm_Wk     = (const float*)d_in[8];
  const float* tm_Wv     = (const float*)d_in[9];
  const float* tm_Wr     = (const float*)d_in[10];
  const float* time_decay= (const float*)d_in[11];
  const float* time_first= (const float*)d_in[12];
  const float* Wo        = (const float*)d_in[13];
  const float* cm_mix_k  = (const float*)d_in[14];
  const float* cm_mix_r  = (const float*)d_in[15];
  const float* cm_Wk     = (const float*)d_in[16];
  const float* cm_Wv     = (const float*)d_in[17];
  const float* cm_Wr     = (const float*)d_in[18];
  float* out = (float*)d_out;
  char* ws = (char*)d_ws;
  const size_t MB = 1024ull * 1024ull;

  // ---- workspace layout, peak 154 MB ----
  _Float16* WkT   = (_Float16*)(ws + 0 * MB);    // 2MB (1024x1024 f16)
  _Float16* WvT   = (_Float16*)(ws + 2 * MB);
  _Float16* WrT   = (_Float16*)(ws + 4 * MB);
  _Float16* WoT   = (_Float16*)(ws + 6 * MB);
  _Float16* cmWkT = (_Float16*)(ws + 8 * MB);    // 8MB (4096x1024)
  _Float16* cmWvT = (_Float16*)(ws + 16 * MB);   // 8MB (1024x4096)
  _Float16* cmWrT = (_Float16*)(ws + 24 * MB);   // 2MB
  // wkv scratch reuses WkT/WvT/WrT slots (dead after k/v/r GEMMs):
  float* aal = (float*)(ws + 0 * MB);            // 1MB each
  float* bbl = (float*)(ws + 1 * MB);
  float* ppl = (float*)(ws + 2 * MB);
  float* aap = (float*)(ws + 3 * MB);
  float* bbp = (float*)(ws + 4 * MB);
  float* ppp = (float*)(ws + 5 * MB);
  // time-mix slots (32MB each):
  _Float16* kbuf  = (_Float16*)(ws + 26 * MB);   // [26,58)  (k output)
  _Float16* xk    = (_Float16*)(ws + 58 * MB);   // [58,90)
  _Float16* xv    = (_Float16*)(ws + 90 * MB);   // [90,122)
  _Float16* xr    = (_Float16*)(ws + 122 * MB);  // [122,154)
  _Float16* kb    = kbuf;
  _Float16* vb    = xk;                          // xk dead after gemm K
  _Float16* rb    = xv;                          // xv dead after gemm V
  _Float16* ab    = xr;                          // xr dead after gemm R
  // channel-mix (full 16384 rows, K-split of the 4096 dim):
  _Float16* xr2   = (_Float16*)(ws + 58 * MB);   // [58,90)  dead before kc
  _Float16* xk2   = (_Float16*)(ws + 90 * MB);   // [90,122)
  _Float16* rc    = (_Float16*)(ws + 122 * MB);  // [122,154)
  _Float16* kc    = (_Float16*)(ws + 26 * MB);   // [26,90) 64MB (16384x2048)

  const int SMEM = 131072;
  static bool attr_done = false;
  if (!attr_done) {
    hipFuncSetAttribute((const void*)gemm8<0>, hipFuncAttributeMaxDynamicSharedMemorySize, SMEM);
    hipFuncSetAttribute((const void*)gemm8<1>, hipFuncAttributeMaxDynamicSharedMemorySize, SMEM);
    hipFuncSetAttribute((const void*)gemm8<2>, hipFuncAttributeMaxDynamicSharedMemorySize, SMEM);
    hipFuncSetAttribute((const void*)gemm8<3>, hipFuncAttributeMaxDynamicSharedMemorySize, SMEM);
    hipFuncSetAttribute((const void*)gemm8<4>, hipFuncAttributeMaxDynamicSharedMemorySize, SMEM);
    attr_done = true;
  }

  // --- weight prep ---
  wtrans_kernel<<<dim3(256), 256, 0, stream>>>(tm_Wk, WkT, 1024, 1024);
  wtrans_kernel<<<dim3(256), 256, 0, stream>>>(tm_Wv, WvT, 1024, 1024);
  wtrans_kernel<<<dim3(256), 256, 0, stream>>>(tm_Wr, WrT, 1024, 1024);
  wtrans_kernel<<<dim3(256), 256, 0, stream>>>(Wo, WoT, 1024, 1024);
  wtrans_kernel<<<dim3(1024), 256, 0, stream>>>(cm_Wk, cmWkT, 1024, 4096);
  wtrans_kernel<<<dim3(1024), 256, 0, stream>>>(cm_Wv, cmWvT, 4096, 1024);
  wtrans_kernel<<<dim3(256), 256, 0, stream>>>(cm_Wr, cmWrT, 1024, 1024);

  // --- time mixing: fused LN1+mix ---
  lnmix_kernel<true><<<dim3(ROWS / 4), 256, 0, stream>>>(
      x_in, ln1_g, ln1_b, tm_mix_k, tm_mix_v, tm_mix_r, xk, xv, xr);
  gemm8<0><<<dim3(64 * 4), 512, SMEM, stream>>>(xk, 1024, WkT, 1024, 1024, 1024,
                                                4, nullptr, kb, nullptr, nullptr);
  gemm8<0><<<dim3(64 * 4), 512, SMEM, stream>>>(xv, 1024, WvT, 1024, 1024, 1024,
                                                4, nullptr, vb, nullptr, nullptr);
  gemm8<0><<<dim3(64 * 4), 512, SMEM, stream>>>(xr, 1024, WrT, 1024, 1024, 1024,
                                                4, nullptr, rb, nullptr, nullptr);
  wkv_pass1<<<dim3(Bb * CC * Hh / 256), 256, 0, stream>>>(kb, vb, time_decay,
                                                          aal, bbl, ppl);
  wkv_pass2<<<dim3(Bb * Hh / 256), 256, 0, stream>>>(time_decay, aal, bbl, ppl,
                                                     aap, bbp, ppp);
  wkv_pass3<<<dim3(Bb * CC * Hh / 256), 256, 0, stream>>>(
      kb, vb, rb, time_decay, time_first, aap, bbp, ppp, ab);
  gemm8<3><<<dim3(64 * 4), 512, SMEM, stream>>>(ab, 1024, WoT, 1024, 1024, 1024,
                                                4, out, nullptr, x_in, nullptr);

  // --- channel mixing: fused LN2+mix, then GEMMs (2 K-halves of 4096) ---
  lnmix_kernel<false><<<dim3(ROWS / 4), 256, 0, stream>>>(
      out, ln2_g, ln2_b, cm_mix_k, nullptr, cm_mix_r, xk2, nullptr, xr2);
  gemm8<2><<<dim3(64 * 4), 512, SMEM, stream>>>(xr2, 1024, cmWrT, 1024, 1024,
                                                1024, 4, nullptr, rc, nullptr,
                                                nullptr);
  for (int half = 0; half < 2; half++) {
    const _Float16* Bk = cmWkT + (size_t)half * 2048 * 1024;  // rows of N-half
    const _Float16* Bv = cmWvT + (size_t)half * 2048;         // K-half cols
    gemm8<1><<<dim3(64 * 8), 512, SMEM, stream>>>(xk2, 1024, Bk, 1024, 2048,
                                                  1024, 8, nullptr, kc, nullptr,
                                                  nullptr);
    gemm8<4><<<dim3(64 * 4), 512, SMEM, stream>>>(kc, 2048, Bv, 4096, 1024,
                                                  2048, 4, out, nullptr, nullptr,
                                                  rc);
  }
}

// Round 12
// 693.546 us; speedup vs baseline: 1.2993x; 1.0181x over previous
//
#include <hip/hip_runtime.h>
#include <stdint.h>
#include <stddef.h>

// RWKV-v4 block, MI355X. B=8 T=2048 E=H=1024, fp32 in/out.
// R12: (1) 7 wtrans dispatches merged into one range-table kernel.
//      (2) ws_size-gated single-pass channel-mix (kc=128MB) — eliminates one
//          RMW pass over `out` + one rc re-read; falls back to 2-half path.
//      GEMM core = R9/R11 2-phase 256x256 (best measured). wkv: 3-pass scan.
#define Bb 8
#define Tt 2048
#define Ee 1024
#define Hh 1024
#define ROWS (Bb * Tt)   // 16384
#define CC 32            // wkv chunks
#define LL 64            // steps per chunk

typedef __attribute__((ext_vector_type(8))) _Float16 half8v;
typedef __attribute__((ext_vector_type(4))) _Float16 half4v;
typedef __attribute__((ext_vector_type(4))) float f32x4;

#define GL2LDS(gp, lp)                                                        \
  __builtin_amdgcn_global_load_lds(                                          \
      (const __attribute__((address_space(1))) void*)(gp),                   \
      (__attribute__((address_space(3))) void*)(lp), 16, 0, 0)

// compiler-visible waitcnt: vmcnt=n, expcnt=7 (no wait), lgkmcnt=15 (no wait)
#define VMCNT(n) __builtin_amdgcn_s_waitcnt(0xF70 | (n))
#define BAR __builtin_amdgcn_s_barrier()
#define SCHED0 __builtin_amdgcn_sched_barrier(0)

// ------- merged weight convert+transpose: 7 weights in one dispatch --------
struct WTEnt { const float* src; _Float16* dst; int K; int N; int nblk; };
struct WTTab { WTEnt e[7]; };

__global__ __launch_bounds__(256)
void wtrans_all(WTTab tab) {
  int b = (int)blockIdx.x;
  const float* W = tab.e[0].src;
  _Float16* Wt = tab.e[0].dst;
  int K = tab.e[0].K, N = tab.e[0].N;
  bool found = false;
#pragma unroll
  for (int i = 0; i < 7; i++) {
    if (!found) {
      if (b < tab.e[i].nblk) {
        W = tab.e[i].src; Wt = tab.e[i].dst;
        K = tab.e[i].K; N = tab.e[i].N;
        found = true;
      } else {
        b -= tab.e[i].nblk;
      }
    }
  }
  __shared__ float tle[64][65];
  const int ntn = N >> 6;
  const int tn = b % ntn;
  const int tk = b / ntn;
  const int tid = threadIdx.x;
  const int r = tid >> 4;
  const int c4 = (tid & 15) * 4;
#pragma unroll
  for (int i = 0; i < 4; i++) {
    const int row = r + i * 16;
    const float4 v = *reinterpret_cast<const float4*>(
        &W[(size_t)(tk * 64 + row) * N + tn * 64 + c4]);
    tle[row][c4] = v.x; tle[row][c4 + 1] = v.y;
    tle[row][c4 + 2] = v.z; tle[row][c4 + 3] = v.w;
  }
  __syncthreads();
#pragma unroll
  for (int j = 0; j < 2; j++) {
    const int ch = tid + j * 256;
    const int n = ch >> 3;
    const int k8 = (ch & 7) * 8;
    half8v o;
#pragma unroll
    for (int m = 0; m < 8; m++) o[m] = (_Float16)tle[k8 + m][n];
    *reinterpret_cast<half8v*>(&Wt[(size_t)(tn * 64 + n) * K + tk * 64 + k8]) = o;
  }
}

// ------- fused LayerNorm + time-shift mix: one wave per output row ---------
template <bool HASV>
__global__ __launch_bounds__(256)
void lnmix_kernel(const float* __restrict__ x, const float* __restrict__ gw,
                  const float* __restrict__ bw,
                  const float* __restrict__ mk, const float* __restrict__ mv,
                  const float* __restrict__ mr,
                  _Float16* __restrict__ xk, _Float16* __restrict__ xv,
                  _Float16* __restrict__ xr) {
  const int row = blockIdx.x * 4 + (threadIdx.x >> 6);
  const int lane = threadIdx.x & 63;
  const int t = row & (Tt - 1);
  const bool hasprev = (t > 0);          // wave-uniform
  const float4* xc = reinterpret_cast<const float4*>(x + (size_t)row * Ee);
  const float4* xp = reinterpret_cast<const float4*>(x + (size_t)(row - 1) * Ee);
  float4 v[4], pv[4];
  float s = 0.f, sq = 0.f, s1 = 0.f, sq1 = 0.f;
#pragma unroll
  for (int i = 0; i < 4; i++) {
    v[i] = xc[lane + i * 64];
    s += v[i].x + v[i].y + v[i].z + v[i].w;
    sq += v[i].x * v[i].x + v[i].y * v[i].y + v[i].z * v[i].z + v[i].w * v[i].w;
    if (hasprev) {
      pv[i] = xp[lane + i * 64];
      s1 += pv[i].x + pv[i].y + pv[i].z + pv[i].w;
      sq1 += pv[i].x * pv[i].x + pv[i].y * pv[i].y + pv[i].z * pv[i].z +
             pv[i].w * pv[i].w;
    } else {
      pv[i] = (float4){0.f, 0.f, 0.f, 0.f};
    }
  }
#pragma unroll
  for (int o = 32; o > 0; o >>= 1) {
    s += __shfl_xor(s, o);
    sq += __shfl_xor(sq, o);
    s1 += __shfl_xor(s1, o);
    sq1 += __shfl_xor(sq1, o);
  }
  const float mu = s * (1.f / Ee);
  const float rs = rsqrtf(sq * (1.f / Ee) - mu * mu + 1e-3f);
  const float mu1 = s1 * (1.f / Ee);
  const float rs1 = hasprev ? rsqrtf(sq1 * (1.f / Ee) - mu1 * mu1 + 1e-3f) : 0.f;
  const float4* gr = reinterpret_cast<const float4*>(gw);
  const float4* br = reinterpret_cast<const float4*>(bw);
#pragma unroll
  for (int i = 0; i < 4; i++) {
    const int c = lane + i * 64;
    const float4 g4 = gr[c], b4 = br[c];
    float h[4], h1[4];
    h[0] = (v[i].x - mu) * rs * g4.x + b4.x;
    h[1] = (v[i].y - mu) * rs * g4.y + b4.y;
    h[2] = (v[i].z - mu) * rs * g4.z + b4.z;
    h[3] = (v[i].w - mu) * rs * g4.w + b4.w;
    if (hasprev) {
      h1[0] = (pv[i].x - mu1) * rs1 * g4.x + b4.x;
      h1[1] = (pv[i].y - mu1) * rs1 * g4.y + b4.y;
      h1[2] = (pv[i].z - mu1) * rs1 * g4.z + b4.z;
      h1[3] = (pv[i].w - mu1) * rs1 * g4.w + b4.w;
    } else {
      h1[0] = h1[1] = h1[2] = h1[3] = 0.f;   // ZeroPadding1D semantics
    }
    const float4 k4 = reinterpret_cast<const float4*>(mk)[c];
    const float4 r4 = reinterpret_cast<const float4*>(mr)[c];
    const float km[4] = {k4.x, k4.y, k4.z, k4.w};
    const float rm[4] = {r4.x, r4.y, r4.z, r4.w};
    const size_t o = (size_t)row * Ee + (size_t)c * 4;
    half4v ok, orr;
#pragma unroll
    for (int j = 0; j < 4; j++) {
      ok[j] = (_Float16)(h[j] * km[j] + h1[j] * (1.f - km[j]));
      orr[j] = (_Float16)(h[j] * rm[j] + h1[j] * (1.f - rm[j]));
    }
    *reinterpret_cast<half4v*>(&xk[o]) = ok;
    *reinterpret_cast<half4v*>(&xr[o]) = orr;
    if constexpr (HASV) {
      const float4 v4 = reinterpret_cast<const float4*>(mv)[c];
      const float vm[4] = {v4.x, v4.y, v4.z, v4.w};
      half4v ov;
#pragma unroll
      for (int j = 0; j < 4; j++)
        ov[j] = (_Float16)(h[j] * vm[j] + h1[j] * (1.f - vm[j]));
      *reinterpret_cast<half4v*>(&xv[o]) = ov;
    }
  }
}

// ---------------- WKV chunked scan -----------------------------------------
__global__ __launch_bounds__(256)
void wkv_pass1(const _Float16* __restrict__ kb, const _Float16* __restrict__ vb,
               const float* __restrict__ decay,
               float* __restrict__ aal, float* __restrict__ bbl,
               float* __restrict__ ppl) {
  const int gid = blockIdx.x * 256 + threadIdx.x;  // B*CC*H
  const int h = gid & 1023;
  const int rest = gid >> 10;
  const int c = rest & (CC - 1);
  const int b = rest >> 5;
  const float w = -__expf(decay[h]);
  const size_t base = ((size_t)b * Tt + (size_t)c * LL) * Hh + h;
  float aa = 0.f, bb = 0.f, pp = -1e38f;
  for (int i0 = 0; i0 < LL; i0 += 8) {
    float kt[8], vt[8];
#pragma unroll
    for (int j = 0; j < 8; j++) {
      const size_t idx = base + (size_t)(i0 + j) * Hh;
      kt[j] = (float)kb[idx];
      vt[j] = (float)vb[idx];
    }
#pragma unroll
    for (int j = 0; j < 8; j++) {
      const float ww2 = pp + w;
      const float q2 = fmaxf(ww2, kt[j]);
      const float e1 = __expf(ww2 - q2);
      const float e2 = __expf(kt[j] - q2);
      aa = e1 * aa + e2 * vt[j];
      bb = e1 * bb + e2;
      pp = q2;
    }
  }
  const int sidx = (b * CC + c) * Hh + h;
  aal[sidx] = aa; bbl[sidx] = bb; ppl[sidx] = pp;
}

__global__ __launch_bounds__(256)
void wkv_pass2(const float* __restrict__ decay,
               const float* __restrict__ aal, const float* __restrict__ bbl,
               const float* __restrict__ ppl,
               float* __restrict__ aap, float* __restrict__ bbp,
               float* __restrict__ ppp) {
  const int gid = blockIdx.x * 256 + threadIdx.x;  // B*H
  const int h = gid & 1023;
  const int b = gid >> 10;
  const float w = -__expf(decay[h]);
  const float Lw = (float)LL * w;
  float aa = 0.f, bb = 0.f, pp = -1e38f;
#pragma unroll
  for (int c = 0; c < CC; c++) {
    const int sidx = (b * CC + c) * Hh + h;
    aap[sidx] = aa; bbp[sidx] = bb; ppp[sidx] = pp;
    const float la = aal[sidx], lb = bbl[sidx], lp = ppl[sidx];
    const float sp = pp + Lw;
    const float q = fmaxf(sp, lp);
    const float e1 = __expf(sp - q);
    const float e2 = __expf(lp - q);
    aa = e1 * aa + e2 * la;
    bb = e1 * bb + e2 * lb;
    pp = q;
  }
}

__global__ __launch_bounds__(256)
void wkv_pass3(const _Float16* __restrict__ kb, const _Float16* __restrict__ vb,
               const _Float16* __restrict__ rb,
               const float* __restrict__ decay, const float* __restrict__ first,
               const float* __restrict__ aap, const float* __restrict__ bbp,
               const float* __restrict__ ppp, _Float16* __restrict__ ab) {
  const int gid = blockIdx.x * 256 + threadIdx.x;  // B*CC*H
  const int h = gid & 1023;
  const int rest = gid >> 10;
  const int c = rest & (CC - 1);
  const int b = rest >> 5;
  const float w = -__expf(decay[h]);
  const float u = first[h];
  const int sidx = (b * CC + c) * Hh + h;
  float aa = aap[sidx], bb = bbp[sidx], pp = ppp[sidx];
  const size_t base = ((size_t)b * Tt + (size_t)c * LL) * Hh + h;
  for (int i0 = 0; i0 < LL; i0 += 8) {
    float kt[8], vt[8], rr[8];
#pragma unroll
    for (int j = 0; j < 8; j++) {
      const size_t idx = base + (size_t)(i0 + j) * Hh;
      kt[j] = (float)kb[idx];
      vt[j] = (float)vb[idx];
      rr[j] = (float)rb[idx];
    }
#pragma unroll
    for (int j = 0; j < 8; j++) {
      const float ww = u + kt[j];
      const float q = fmaxf(pp, ww);
      const float e1 = __expf(pp - q);
      const float e2 = __expf(ww - q);
      const float out = (e1 * aa + e2 * vt[j]) / (e1 * bb + e2);
      const float sr = 1.f / (1.f + __expf(-rr[j]));
      ab[base + (size_t)(i0 + j) * Hh] = (_Float16)(sr * out);
      const float ww2 = pp + w;
      const float q2 = fmaxf(ww2, kt[j]);
      const float e1b = __expf(ww2 - q2);
      const float e2b = __expf(kt[j] - q2);
      aa = e1b * aa + e2b * vt[j];
      bb = e1b * bb + e2b;
      pp = q2;
    }
  }
}

// ---------------- 256x256 2-phase GEMM: C = A(MxK) * Bt(NxK)^T, f16 --------
// (R9 form — best measured. XOR-swizzled LDS, counted vmcnt, 4 barriers/tile.)
// EPI: 0 f16; 1 relu^2 f16; 2 sigmoid f16; 3 f32 res+val; 4 f32 += scale*val
template <int EPI>
__global__ __launch_bounds__(512, 2)
void gemm8(const _Float16* __restrict__ A, const int ldA,
           const _Float16* __restrict__ Bt, const int ldB,
           const int N, const int K, const int nbx,
           float* __restrict__ outF, _Float16* __restrict__ outH,
           const float* __restrict__ res, const _Float16* __restrict__ scale) {
  extern __shared__ _Float16 smem[];
  _Float16* sA = smem;               // [2][256*64]
  _Float16* sB = smem + 2 * 16384;   // [2][256*64]
  const int tid = threadIdx.x;
  const int lane = tid & 63;
  const int w = tid >> 6;
  const int wm = w >> 2, wn = w & 3;
  const int r0 = lane & 15, kg = lane >> 4;
  // bijective XCD swizzle (gridDim.x % 8 == 0)
  const int cpx = gridDim.x >> 3;
  const int wg = ((int)blockIdx.x & 7) * cpx + ((int)blockIdx.x >> 3);
  const int bm = (wg / nbx) * 256;
  const int bn = (wg % nbx) * 256;
  const int NT = K >> 6;

  f32x4 acc[8][4];
#pragma unroll
  for (int i = 0; i < 8; i++)
#pragma unroll
    for (int j = 0; j < 4; j++) acc[i][j] = (f32x4){0.f, 0.f, 0.f, 0.f};

  auto stage = [&](const _Float16* __restrict__ G, const int ldG,
                   const int growbase, const int t, _Float16* sX, const int hb) {
    _Float16* base = sX + (t & 1) * 16384 + hb * 8192;
#pragma unroll
    for (int i = 0; i < 2; i++) {
      const int rih = (w * 2 + i) * 8 + (lane >> 3);
      const int gs = (lane & 7) ^ (rih & 7);
      GL2LDS(G + (size_t)(growbase + hb * 128 + rih) * ldG + (size_t)t * 64 + gs * 8,
             base + (w * 2 + i) * 512);
    }
  };
  auto rdA = [&](int p, int row, int ks) -> half8v {
    return *reinterpret_cast<const half8v*>(
        sA + p * 16384 + row * 64 + ((ks ^ (row & 7)) << 3));
  };
  auto rdB = [&](int p, int row, int ks) -> half8v {
    return *reinterpret_cast<const half8v*>(
        sB + p * 16384 + row * 64 + ((ks ^ (row & 7)) << 3));
  };

  // prologue: tile0 (A0,A1,B1,B0) + tile1 (A0,A1); drain tile0, keep A(1)
  stage(A, ldA, bm, 0, sA, 0);
  stage(A, ldA, bm, 0, sA, 1);
  stage(Bt, ldB, bn, 0, sB, 1);
  stage(Bt, ldB, bn, 0, sB, 0);
  if (NT > 1) { stage(A, ldA, bm, 1, sA, 0); stage(A, ldA, bm, 1, sA, 1); }
  VMCNT(4);
  BAR;
  SCHED0;

  for (int t = 0; t < NT; ++t) {
    const int p = t & 1;
    half8v a0[4][2], a1[4][2], b0[2][2], b1[2][2];
    // ---- phase 1: stage B(t+1); read ALL 24 frags; MFMA a0/a1 x b0 ----
    if (t + 1 < NT) {
      stage(Bt, ldB, bn, t + 1, sB, 1);
      stage(Bt, ldB, bn, t + 1, sB, 0);
    }
#pragma unroll
    for (int fr = 0; fr < 4; fr++)
#pragma unroll
      for (int kk = 0; kk < 2; kk++)
        a0[fr][kk] = rdA(p, wm * 128 + fr * 16 + r0, kk * 4 + kg);
#pragma unroll
    for (int fr = 0; fr < 4; fr++)
#pragma unroll
      for (int kk = 0; kk < 2; kk++)
        a1[fr][kk] = rdA(p, wm * 128 + 64 + fr * 16 + r0, kk * 4 + kg);
#pragma unroll
    for (int fc = 0; fc < 2; fc++)
#pragma unroll
      for (int kk = 0; kk < 2; kk++)
        b0[fc][kk] = rdB(p, wn * 64 + fc * 16 + r0, kk * 4 + kg);
#pragma unroll
    for (int fc = 0; fc < 2; fc++)
#pragma unroll
      for (int kk = 0; kk < 2; kk++)
        b1[fc][kk] = rdB(p, wn * 64 + 32 + fc * 16 + r0, kk * 4 + kg);
    BAR;
    __builtin_amdgcn_s_setprio(1);
#pragma unroll
    for (int fr = 0; fr < 4; fr++)
#pragma unroll
      for (int fc = 0; fc < 2; fc++)
#pragma unroll
        for (int kk = 0; kk < 2; kk++)
          acc[fr][fc] = __builtin_amdgcn_mfma_f32_16x16x32_f16(
              a0[fr][kk], b0[fc][kk], acc[fr][fc], 0, 0, 0);
#pragma unroll
    for (int fr = 0; fr < 4; fr++)
#pragma unroll
      for (int fc = 0; fc < 2; fc++)
#pragma unroll
        for (int kk = 0; kk < 2; kk++)
          acc[4 + fr][fc] = __builtin_amdgcn_mfma_f32_16x16x32_f16(
              a1[fr][kk], b0[fc][kk], acc[4 + fr][fc], 0, 0, 0);
    __builtin_amdgcn_s_setprio(0);
    SCHED0;
    BAR;
    // ---- phase 2: stage A(t+2); counted vmcnt; MFMA a1/a0 x b1 ----
    if (t + 2 < NT) {
      stage(A, ldA, bm, t + 2, sA, 0);
      stage(A, ldA, bm, t + 2, sA, 1);
      VMCNT(4);
    } else {
      VMCNT(0);
    }
    BAR;
    __builtin_amdgcn_s_setprio(1);
#pragma unroll
    for (int fr = 0; fr < 4; fr++)
#pragma unroll
      for (int fc = 0; fc < 2; fc++)
#pragma unroll
        for (int kk = 0; kk < 2; kk++)
          acc[4 + fr][2 + fc] = __builtin_amdgcn_mfma_f32_16x16x32_f16(
              a1[fr][kk], b1[fc][kk], acc[4 + fr][2 + fc], 0, 0, 0);
#pragma unroll
    for (int fr = 0; fr < 4; fr++)
#pragma unroll
      for (int fc = 0; fc < 2; fc++)
#pragma unroll
        for (int kk = 0; kk < 2; kk++)
          acc[fr][2 + fc] = __builtin_amdgcn_mfma_f32_16x16x32_f16(
              a0[fr][kk], b1[fc][kk], acc[fr][2 + fc], 0, 0, 0);
    __builtin_amdgcn_s_setprio(0);
    SCHED0;
    BAR;
  }
  VMCNT(0);

  // epilogue
#pragma unroll
  for (int fr = 0; fr < 8; fr++) {
#pragma unroll
    for (int fc = 0; fc < 4; fc++) {
#pragma unroll
      for (int i = 0; i < 4; i++) {
        const int row = bm + wm * 128 + fr * 16 + (lane >> 4) * 4 + i;
        const int col = bn + wn * 64 + fc * 16 + r0;
        const size_t idx = (size_t)row * N + col;
        const float val = acc[fr][fc][i];
        if constexpr (EPI == 0) {
          outH[idx] = (_Float16)val;
        } else if constexpr (EPI == 1) {
          const float tt = fmaxf(val, 0.f);
          outH[idx] = (_Float16)(tt * tt);
        } else if constexpr (EPI == 2) {
          outH[idx] = (_Float16)(1.f / (1.f + __expf(-val)));
        } else if constexpr (EPI == 3) {
          outF[idx] = res[idx] + val;
        } else {
          outF[idx] = outF[idx] + (float)scale[idx] * val;
        }
      }
    }
  }
}

// ---------------------------------------------------------------------------
extern "C" void kernel_launch(void* const* d_in, const int* in_sizes, int n_in,
                              void* d_out, int out_size, void* d_ws,
                              size_t ws_size, hipStream_t stream) {
  (void)in_sizes; (void)n_in; (void)out_size;
  const float* x_in      = (const float*)d_in[0];
  const float* ln1_g     = (const float*)d_in[1];
  const float* ln1_b     = (const float*)d_in[2];
  const float* ln2_g     = (const float*)d_in[3];
  const float* ln2_b     = (const float*)d_in[4];
  const float* tm_mix_k  = (const float*)d_in[5];
  const float* tm_mix_v  = (const float*)d_in[6];
  const float* tm_mix_r  = (const float*)d_in[7];
  const float* tm_Wk     = (const float*)d_in[8];
  const float* tm_Wv     = (const float*)d_in[9];
  const float* tm_Wr     = (const float*)d_in[10];
  const float* time_decay= (const float*)d_in[11];
  const float* time_first= (const float*)d_in[12];
  const float* Wo        = (const float*)d_in[13];
  const float* cm_mix_k  = (const float*)d_in[14];
  const float* cm_mix_r  = (const float*)d_in[15];
  const float* cm_Wk     = (const float*)d_in[16];
  const float* cm_Wv     = (const float*)d_in[17];
  const float* cm_Wr     = (const float*)d_in[18];
  float* out = (float*)d_out;
  char* ws = (char*)d_ws;
  const size_t MB = 1024ull * 1024ull;

  // ---- workspace layout ----
  _Float16* WkT   = (_Float16*)(ws + 0 * MB);    // 2MB (1024x1024 f16)
  _Float16* WvT   = (_Float16*)(ws + 2 * MB);
  _Float16* WrT   = (_Float16*)(ws + 4 * MB);
  _Float16* WoT   = (_Float16*)(ws + 6 * MB);
  _Float16* cmWkT = (_Float16*)(ws + 8 * MB);    // 8MB (4096x1024)
  _Float16* cmWvT = (_Float16*)(ws + 16 * MB);   // 8MB (1024x4096)
  _Float16* cmWrT = (_Float16*)(ws + 24 * MB);   // 2MB
  // wkv scratch reuses WkT/WvT/WrT slots (dead after k/v/r GEMMs):
  float* aal = (float*)(ws + 0 * MB);            // 1MB each
  float* bbl = (float*)(ws + 1 * MB);
  float* ppl = (float*)(ws + 2 * MB);
  float* aap = (float*)(ws + 3 * MB);
  float* bbp = (float*)(ws + 4 * MB);
  float* ppp = (float*)(ws + 5 * MB);
  // time-mix slots (32MB each):
  _Float16* kbuf  = (_Float16*)(ws + 26 * MB);   // [26,58)
  _Float16* xk    = (_Float16*)(ws + 58 * MB);   // [58,90)
  _Float16* xv    = (_Float16*)(ws + 90 * MB);   // [90,122)
  _Float16* xr    = (_Float16*)(ws + 122 * MB);  // [122,154)
  _Float16* kb    = kbuf;
  _Float16* vb    = xk;                          // xk dead after gemm K
  _Float16* rb    = xv;                          // xv dead after gemm V
  _Float16* ab    = xr;                          // xr dead after gemm R

  const int SMEM = 131072;
  static bool attr_done = false;
  if (!attr_done) {
    hipFuncSetAttribute((const void*)gemm8<0>, hipFuncAttributeMaxDynamicSharedMemorySize, SMEM);
    hipFuncSetAttribute((const void*)gemm8<1>, hipFuncAttributeMaxDynamicSharedMemorySize, SMEM);
    hipFuncSetAttribute((const void*)gemm8<2>, hipFuncAttributeMaxDynamicSharedMemorySize, SMEM);
    hipFuncSetAttribute((const void*)gemm8<3>, hipFuncAttributeMaxDynamicSharedMemorySize, SMEM);
    hipFuncSetAttribute((const void*)gemm8<4>, hipFuncAttributeMaxDynamicSharedMemorySize, SMEM);
    attr_done = true;
  }

  // --- weight prep: all 7 transposes in ONE dispatch ---
  WTTab tab;
  tab.e[0] = {tm_Wk, WkT,   1024, 1024, 256};
  tab.e[1] = {tm_Wv, WvT,   1024, 1024, 256};
  tab.e[2] = {tm_Wr, WrT,   1024, 1024, 256};
  tab.e[3] = {Wo,    WoT,   1024, 1024, 256};
  tab.e[4] = {cm_Wk, cmWkT, 1024, 4096, 1024};
  tab.e[5] = {cm_Wv, cmWvT, 4096, 1024, 1024};
  tab.e[6] = {cm_Wr, cmWrT, 1024, 1024, 256};
  wtrans_all<<<dim3(3328), 256, 0, stream>>>(tab);

  // --- time mixing: fused LN1+mix ---
  lnmix_kernel<true><<<dim3(ROWS / 4), 256, 0, stream>>>(
      x_in, ln1_g, ln1_b, tm_mix_k, tm_mix_v, tm_mix_r, xk, xv, xr);
  gemm8<0><<<dim3(64 * 4), 512, SMEM, stream>>>(xk, 1024, WkT, 1024, 1024, 1024,
                                                4, nullptr, kb, nullptr, nullptr);
  gemm8<0><<<dim3(64 * 4), 512, SMEM, stream>>>(xv, 1024, WvT, 1024, 1024, 1024,
                                                4, nullptr, vb, nullptr, nullptr);
  gemm8<0><<<dim3(64 * 4), 512, SMEM, stream>>>(xr, 1024, WrT, 1024, 1024, 1024,
                                                4, nullptr, rb, nullptr, nullptr);
  wkv_pass1<<<dim3(Bb * CC * Hh / 256), 256, 0, stream>>>(kb, vb, time_decay,
                                                          aal, bbl, ppl);
  wkv_pass2<<<dim3(Bb * Hh / 256), 256, 0, stream>>>(time_decay, aal, bbl, ppl,
                                                     aap, bbp, ppp);
  wkv_pass3<<<dim3(Bb * CC * Hh / 256), 256, 0, stream>>>(
      kb, vb, rb, time_decay, time_first, aap, bbp, ppp, ab);
  gemm8<3><<<dim3(64 * 4), 512, SMEM, stream>>>(ab, 1024, WoT, 1024, 1024, 1024,
                                                4, out, nullptr, x_in, nullptr);

  // --- channel mixing ---
  if (ws_size >= 250ull * MB) {
    // single-pass: kc = 16384x4096 f16 (128MB); one RMW pass over `out`
    _Float16* xk2s = (_Float16*)(ws + 26 * MB);   // [26,58)
    _Float16* rcs  = (_Float16*)(ws + 58 * MB);   // [58,90)
    _Float16* kcs  = (_Float16*)(ws + 90 * MB);   // [90,218)
    _Float16* xr2s = (_Float16*)(ws + 218 * MB);  // [218,250)
    lnmix_kernel<false><<<dim3(ROWS / 4), 256, 0, stream>>>(
        out, ln2_g, ln2_b, cm_mix_k, nullptr, cm_mix_r, xk2s, nullptr, xr2s);
    gemm8<2><<<dim3(64 * 4), 512, SMEM, stream>>>(xr2s, 1024, cmWrT, 1024, 1024,
                                                  1024, 4, nullptr, rcs, nullptr,
                                                  nullptr);
    gemm8<1><<<dim3(64 * 16), 512, SMEM, stream>>>(xk2s, 1024, cmWkT, 1024,
                                                   4096, 1024, 16, nullptr, kcs,
                                                   nullptr, nullptr);
    gemm8<4><<<dim3(64 * 4), 512, SMEM, stream>>>(kcs, 4096, cmWvT, 4096, 1024,
                                                  4096, 4, out, nullptr, nullptr,
                                                  rcs);
  } else {
    // two-half fallback (154MB peak, proven)
    _Float16* xr2   = (_Float16*)(ws + 58 * MB);   // [58,90)
    _Float16* xk2   = (_Float16*)(ws + 90 * MB);   // [90,122)
    _Float16* rc    = (_Float16*)(ws + 122 * MB);  // [122,154)
    _Float16* kc    = (_Float16*)(ws + 26 * MB);   // [26,90) 64MB
    lnmix_kernel<false><<<dim3(ROWS / 4), 256, 0, stream>>>(
        out, ln2_g, ln2_b, cm_mix_k, nullptr, cm_mix_r, xk2, nullptr, xr2);
    gemm8<2><<<dim3(64 * 4), 512, SMEM, stream>>>(xr2, 1024, cmWrT, 1024, 1024,
                                                  1024, 4, nullptr, rc, nullptr,
                                                  nullptr);
    for (int half = 0; half < 2; half++) {
      const _Float16* Bk = cmWkT + (size_t)half * 2048 * 1024;  // N-half rows
      const _Float16* Bv = cmWvT + (size_t)half * 2048;         // K-half cols
      gemm8<1><<<dim3(64 * 8), 512, SMEM, stream>>>(xk2, 1024, Bk, 1024, 2048,
                                                    1024, 8, nullptr, kc,
                                                    nullptr, nullptr);
      gemm8<4><<<dim3(64 * 4), 512, SMEM, stream>>>(kc, 2048, Bv, 4096, 1024,
                                                    2048, 4, out, nullptr,
                                                    nullptr, rc);
    }
  }
}

// Round 13
// 692.952 us; speedup vs baseline: 1.3004x; 1.0009x over previous
//
#include <hip/hip_runtime.h>
#include <stdint.h>
#include <stddef.h>

// RWKV-v4 block, MI355X. B=8 T=2048 E=H=1024, fp32 in/out.
// R12: (1) 7 wtrans dispatches merged into one range-table kernel.
//      (2) ws_size-gated single-pass channel-mix (kc=128MB) — eliminates one
//          RMW pass over `out` + one rc re-read; falls back to 2-half path.
//      GEMM core = R9/R11 2-phase 256x256 (best measured). wkv: 3-pass scan.
#define Bb 8
#define Tt 2048
#define Ee 1024
#define Hh 1024
#define ROWS (Bb * Tt)   // 16384
#define CC 32            // wkv chunks
#define LL 64            // steps per chunk

typedef __attribute__((ext_vector_type(8))) _Float16 half8v;
typedef __attribute__((ext_vector_type(4))) _Float16 half4v;
typedef __attribute__((ext_vector_type(4))) float f32x4;

#define GL2LDS(gp, lp)                                                        \
  __builtin_amdgcn_global_load_lds(                                          \
      (const __attribute__((address_space(1))) void*)(gp),                   \
      (__attribute__((address_space(3))) void*)(lp), 16, 0, 0)

// compiler-visible waitcnt: vmcnt=n, expcnt=7 (no wait), lgkmcnt=15 (no wait)
#define VMCNT(n) __builtin_amdgcn_s_waitcnt(0xF70 | (n))
#define BAR __builtin_amdgcn_s_barrier()
#define SCHED0 __builtin_amdgcn_sched_barrier(0)

// ------- merged weight convert+transpose: 7 weights in one dispatch --------
struct WTEnt { const float* src; _Float16* dst; int K; int N; int nblk; };
struct WTTab { WTEnt e[7]; };

__global__ __launch_bounds__(256)
void wtrans_all(WTTab tab) {
  int b = (int)blockIdx.x;
  const float* W = tab.e[0].src;
  _Float16* Wt = tab.e[0].dst;
  int K = tab.e[0].K, N = tab.e[0].N;
  bool found = false;
#pragma unroll
  for (int i = 0; i < 7; i++) {
    if (!found) {
      if (b < tab.e[i].nblk) {
        W = tab.e[i].src; Wt = tab.e[i].dst;
        K = tab.e[i].K; N = tab.e[i].N;
        found = true;
      } else {
        b -= tab.e[i].nblk;
      }
    }
  }
  __shared__ float tle[64][65];
  const int ntn = N >> 6;
  const int tn = b % ntn;
  const int tk = b / ntn;
  const int tid = threadIdx.x;
  const int r = tid >> 4;
  const int c4 = (tid & 15) * 4;
#pragma unroll
  for (int i = 0; i < 4; i++) {
    const int row = r + i * 16;
    const float4 v = *reinterpret_cast<const float4*>(
        &W[(size_t)(tk * 64 + row) * N + tn * 64 + c4]);
    tle[row][c4] = v.x; tle[row][c4 + 1] = v.y;
    tle[row][c4 + 2] = v.z; tle[row][c4 + 3] = v.w;
  }
  __syncthreads();
#pragma unroll
  for (int j = 0; j < 2; j++) {
    const int ch = tid + j * 256;
    const int n = ch >> 3;
    const int k8 = (ch & 7) * 8;
    half8v o;
#pragma unroll
    for (int m = 0; m < 8; m++) o[m] = (_Float16)tle[k8 + m][n];
    *reinterpret_cast<half8v*>(&Wt[(size_t)(tn * 64 + n) * K + tk * 64 + k8]) = o;
  }
}

// ------- fused LayerNorm + time-shift mix: one wave per output row ---------
template <bool HASV>
__global__ __launch_bounds__(256)
void lnmix_kernel(const float* __restrict__ x, const float* __restrict__ gw,
                  const float* __restrict__ bw,
                  const float* __restrict__ mk, const float* __restrict__ mv,
                  const float* __restrict__ mr,
                  _Float16* __restrict__ xk, _Float16* __restrict__ xv,
                  _Float16* __restrict__ xr) {
  const int row = blockIdx.x * 4 + (threadIdx.x >> 6);
  const int lane = threadIdx.x & 63;
  const int t = row & (Tt - 1);
  const bool hasprev = (t > 0);          // wave-uniform
  const float4* xc = reinterpret_cast<const float4*>(x + (size_t)row * Ee);
  const float4* xp = reinterpret_cast<const float4*>(x + (size_t)(row - 1) * Ee);
  float4 v[4], pv[4];
  float s = 0.f, sq = 0.f, s1 = 0.f, sq1 = 0.f;
#pragma unroll
  for (int i = 0; i < 4; i++) {
    v[i] = xc[lane + i * 64];
    s += v[i].x + v[i].y + v[i].z + v[i].w;
    sq += v[i].x * v[i].x + v[i].y * v[i].y + v[i].z * v[i].z + v[i].w * v[i].w;
    if (hasprev) {
      pv[i] = xp[lane + i * 64];
      s1 += pv[i].x + pv[i].y + pv[i].z + pv[i].w;
      sq1 += pv[i].x * pv[i].x + pv[i].y * pv[i].y + pv[i].z * pv[i].z +
             pv[i].w * pv[i].w;
    } else {
      pv[i] = (float4){0.f, 0.f, 0.f, 0.f};
    }
  }
#pragma unroll
  for (int o = 32; o > 0; o >>= 1) {
    s += __shfl_xor(s, o);
    sq += __shfl_xor(sq, o);
    s1 += __shfl_xor(s1, o);
    sq1 += __shfl_xor(sq1, o);
  }
  const float mu = s * (1.f / Ee);
  const float rs = rsqrtf(sq * (1.f / Ee) - mu * mu + 1e-3f);
  const float mu1 = s1 * (1.f / Ee);
  const float rs1 = hasprev ? rsqrtf(sq1 * (1.f / Ee) - mu1 * mu1 + 1e-3f) : 0.f;
  const float4* gr = reinterpret_cast<const float4*>(gw);
  const float4* br = reinterpret_cast<const float4*>(bw);
#pragma unroll
  for (int i = 0; i < 4; i++) {
    const int c = lane + i * 64;
    const float4 g4 = gr[c], b4 = br[c];
    float h[4], h1[4];
    h[0] = (v[i].x - mu) * rs * g4.x + b4.x;
    h[1] = (v[i].y - mu) * rs * g4.y + b4.y;
    h[2] = (v[i].z - mu) * rs * g4.z + b4.z;
    h[3] = (v[i].w - mu) * rs * g4.w + b4.w;
    if (hasprev) {
      h1[0] = (pv[i].x - mu1) * rs1 * g4.x + b4.x;
      h1[1] = (pv[i].y - mu1) * rs1 * g4.y + b4.y;
      h1[2] = (pv[i].z - mu1) * rs1 * g4.z + b4.z;
      h1[3] = (pv[i].w - mu1) * rs1 * g4.w + b4.w;
    } else {
      h1[0] = h1[1] = h1[2] = h1[3] = 0.f;   // ZeroPadding1D semantics
    }
    const float4 k4 = reinterpret_cast<const float4*>(mk)[c];
    const float4 r4 = reinterpret_cast<const float4*>(mr)[c];
    const float km[4] = {k4.x, k4.y, k4.z, k4.w};
    const float rm[4] = {r4.x, r4.y, r4.z, r4.w};
    const size_t o = (size_t)row * Ee + (size_t)c * 4;
    half4v ok, orr;
#pragma unroll
    for (int j = 0; j < 4; j++) {
      ok[j] = (_Float16)(h[j] * km[j] + h1[j] * (1.f - km[j]));
      orr[j] = (_Float16)(h[j] * rm[j] + h1[j] * (1.f - rm[j]));
    }
    *reinterpret_cast<half4v*>(&xk[o]) = ok;
    *reinterpret_cast<half4v*>(&xr[o]) = orr;
    if constexpr (HASV) {
      const float4 v4 = reinterpret_cast<const float4*>(mv)[c];
      const float vm[4] = {v4.x, v4.y, v4.z, v4.w};
      half4v ov;
#pragma unroll
      for (int j = 0; j < 4; j++)
        ov[j] = (_Float16)(h[j] * vm[j] + h1[j] * (1.f - vm[j]));
      *reinterpret_cast<half4v*>(&xv[o]) = ov;
    }
  }
}

// ---------------- WKV chunked scan -----------------------------------------
__global__ __launch_bounds__(256)
void wkv_pass1(const _Float16* __restrict__ kb, const _Float16* __restrict__ vb,
               const float* __restrict__ decay,
               float* __restrict__ aal, float* __restrict__ bbl,
               float* __restrict__ ppl) {
  const int gid = blockIdx.x * 256 + threadIdx.x;  // B*CC*H
  const int h = gid & 1023;
  const int rest = gid >> 10;
  const int c = rest & (CC - 1);
  const int b = rest >> 5;
  const float w = -__expf(decay[h]);
  const size_t base = ((size_t)b * Tt + (size_t)c * LL) * Hh + h;
  float aa = 0.f, bb = 0.f, pp = -1e38f;
  for (int i0 = 0; i0 < LL; i0 += 8) {
    float kt[8], vt[8];
#pragma unroll
    for (int j = 0; j < 8; j++) {
      const size_t idx = base + (size_t)(i0 + j) * Hh;
      kt[j] = (float)kb[idx];
      vt[j] = (float)vb[idx];
    }
#pragma unroll
    for (int j = 0; j < 8; j++) {
      const float ww2 = pp + w;
      const float q2 = fmaxf(ww2, kt[j]);
      const float e1 = __expf(ww2 - q2);
      const float e2 = __expf(kt[j] - q2);
      aa = e1 * aa + e2 * vt[j];
      bb = e1 * bb + e2;
      pp = q2;
    }
  }
  const int sidx = (b * CC + c) * Hh + h;
  aal[sidx] = aa; bbl[sidx] = bb; ppl[sidx] = pp;
}

__global__ __launch_bounds__(256)
void wkv_pass2(const float* __restrict__ decay,
               const float* __restrict__ aal, const float* __restrict__ bbl,
               const float* __restrict__ ppl,
               float* __restrict__ aap, float* __restrict__ bbp,
               float* __restrict__ ppp) {
  const int gid = blockIdx.x * 256 + threadIdx.x;  // B*H
  const int h = gid & 1023;
  const int b = gid >> 10;
  const float w = -__expf(decay[h]);
  const float Lw = (float)LL * w;
  float aa = 0.f, bb = 0.f, pp = -1e38f;
#pragma unroll
  for (int c = 0; c < CC; c++) {
    const int sidx = (b * CC + c) * Hh + h;
    aap[sidx] = aa; bbp[sidx] = bb; ppp[sidx] = pp;
    const float la = aal[sidx], lb = bbl[sidx], lp = ppl[sidx];
    const float sp = pp + Lw;
    const float q = fmaxf(sp, lp);
    const float e1 = __expf(sp - q);
    const float e2 = __expf(lp - q);
    aa = e1 * aa + e2 * la;
    bb = e1 * bb + e2 * lb;
    pp = q;
  }
}

__global__ __launch_bounds__(256)
void wkv_pass3(const _Float16* __restrict__ kb, const _Float16* __restrict__ vb,
               const _Float16* __restrict__ rb,
               const float* __restrict__ decay, const float* __restrict__ first,
               const float* __restrict__ aap, const float* __restrict__ bbp,
               const float* __restrict__ ppp, _Float16* __restrict__ ab) {
  const int gid = blockIdx.x * 256 + threadIdx.x;  // B*CC*H
  const int h = gid & 1023;
  const int rest = gid >> 10;
  const int c = rest & (CC - 1);
  const int b = rest >> 5;
  const float w = -__expf(decay[h]);
  const float u = first[h];
  const int sidx = (b * CC + c) * Hh + h;
  float aa = aap[sidx], bb = bbp[sidx], pp = ppp[sidx];
  const size_t base = ((size_t)b * Tt + (size_t)c * LL) * Hh + h;
  for (int i0 = 0; i0 < LL; i0 += 8) {
    float kt[8], vt[8], rr[8];
#pragma unroll
    for (int j = 0; j < 8; j++) {
      const size_t idx = base + (size_t)(i0 + j) * Hh;
      kt[j] = (float)kb[idx];
      vt[j] = (float)vb[idx];
      rr[j] = (float)rb[idx];
    }
#pragma unroll
    for (int j = 0; j < 8; j++) {
      const float ww = u + kt[j];
      const float q = fmaxf(pp, ww);
      const float e1 = __expf(pp - q);
      const float e2 = __expf(ww - q);
      const float out = (e1 * aa + e2 * vt[j]) / (e1 * bb + e2);
      const float sr = 1.f / (1.f + __expf(-rr[j]));
      ab[base + (size_t)(i0 + j) * Hh] = (_Float16)(sr * out);
      const float ww2 = pp + w;
      const float q2 = fmaxf(ww2, kt[j]);
      const float e1b = __expf(ww2 - q2);
      const float e2b = __expf(kt[j] - q2);
      aa = e1b * aa + e2b * vt[j];
      bb = e1b * bb + e2b;
      pp = q2;
    }
  }
}

// ---------------- 256x256 2-phase GEMM: C = A(MxK) * Bt(NxK)^T, f16 --------
// (R9 form — best measured. XOR-swizzled LDS, counted vmcnt, 4 barriers/tile.)
// EPI: 0 f16; 1 relu^2 f16; 2 sigmoid f16; 3 f32 res+val; 4 f32 += scale*val
template <int EPI>
__global__ __launch_bounds__(512, 2)
void gemm8(const _Float16* __restrict__ A, const int ldA,
           const _Float16* __restrict__ Bt, const int ldB,
           const int N, const int K, const int nbx,
           float* __restrict__ outF, _Float16* __restrict__ outH,
           const float* __restrict__ res, const _Float16* __restrict__ scale) {
  extern __shared__ _Float16 smem[];
  _Float16* sA = smem;               // [2][256*64]
  _Float16* sB = smem + 2 * 16384;   // [2][256*64]
  const int tid = threadIdx.x;
  const int lane = tid & 63;
  const int w = tid >> 6;
  const int wm = w >> 2, wn = w & 3;
  const int r0 = lane & 15, kg = lane >> 4;
  // bijective XCD swizzle (gridDim.x % 8 == 0)
  const int cpx = gridDim.x >> 3;
  const int wg = ((int)blockIdx.x & 7) * cpx + ((int)blockIdx.x >> 3);
  const int bm = (wg / nbx) * 256;
  const int bn = (wg % nbx) * 256;
  const int NT = K >> 6;

  f32x4 acc[8][4];
#pragma unroll
  for (int i = 0; i < 8; i++)
#pragma unroll
    for (int j = 0; j < 4; j++) acc[i][j] = (f32x4){0.f, 0.f, 0.f, 0.f};

  auto stage = [&](const _Float16* __restrict__ G, const int ldG,
                   const int growbase, const int t, _Float16* sX, const int hb) {
    _Float16* base = sX + (t & 1) * 16384 + hb * 8192;
#pragma unroll
    for (int i = 0; i < 2; i++) {
      const int rih = (w * 2 + i) * 8 + (lane >> 3);
      const int gs = (lane & 7) ^ (rih & 7);
      GL2LDS(G + (size_t)(growbase + hb * 128 + rih) * ldG + (size_t)t * 64 + gs * 8,
             base + (w * 2 + i) * 512);
    }
  };
  auto rdA = [&](int p, int row, int ks) -> half8v {
    return *reinterpret_cast<const half8v*>(
        sA + p * 16384 + row * 64 + ((ks ^ (row & 7)) << 3));
  };
  auto rdB = [&](int p, int row, int ks) -> half8v {
    return *reinterpret_cast<const half8v*>(
        sB + p * 16384 + row * 64 + ((ks ^ (row & 7)) << 3));
  };

  // prologue: tile0 (A0,A1,B1,B0) + tile1 (A0,A1); drain tile0, keep A(1)
  stage(A, ldA, bm, 0, sA, 0);
  stage(A, ldA, bm, 0, sA, 1);
  stage(Bt, ldB, bn, 0, sB, 1);
  stage(Bt, ldB, bn, 0, sB, 0);
  if (NT > 1) { stage(A, ldA, bm, 1, sA, 0); stage(A, ldA, bm, 1, sA, 1); }
  VMCNT(4);
  BAR;
  SCHED0;

  for (int t = 0; t < NT; ++t) {
    const int p = t & 1;
    half8v a0[4][2], a1[4][2], b0[2][2], b1[2][2];
    // ---- phase 1: stage B(t+1); read ALL 24 frags; MFMA a0/a1 x b0 ----
    if (t + 1 < NT) {
      stage(Bt, ldB, bn, t + 1, sB, 1);
      stage(Bt, ldB, bn, t + 1, sB, 0);
    }
#pragma unroll
    for (int fr = 0; fr < 4; fr++)
#pragma unroll
      for (int kk = 0; kk < 2; kk++)
        a0[fr][kk] = rdA(p, wm * 128 + fr * 16 + r0, kk * 4 + kg);
#pragma unroll
    for (int fr = 0; fr < 4; fr++)
#pragma unroll
      for (int kk = 0; kk < 2; kk++)
        a1[fr][kk] = rdA(p, wm * 128 + 64 + fr * 16 + r0, kk * 4 + kg);
#pragma unroll
    for (int fc = 0; fc < 2; fc++)
#pragma unroll
      for (int kk = 0; kk < 2; kk++)
        b0[fc][kk] = rdB(p, wn * 64 + fc * 16 + r0, kk * 4 + kg);
#pragma unroll
    for (int fc = 0; fc < 2; fc++)
#pragma unroll
      for (int kk = 0; kk < 2; kk++)
        b1[fc][kk] = rdB(p, wn * 64 + 32 + fc * 16 + r0, kk * 4 + kg);
    BAR;
    __builtin_amdgcn_s_setprio(1);
#pragma unroll
    for (int fr = 0; fr < 4; fr++)
#pragma unroll
      for (int fc = 0; fc < 2; fc++)
#pragma unroll
        for (int kk = 0; kk < 2; kk++)
          acc[fr][fc] = __builtin_amdgcn_mfma_f32_16x16x32_f16(
              a0[fr][kk], b0[fc][kk], acc[fr][fc], 0, 0, 0);
#pragma unroll
    for (int fr = 0; fr < 4; fr++)
#pragma unroll
      for (int fc = 0; fc < 2; fc++)
#pragma unroll
        for (int kk = 0; kk < 2; kk++)
          acc[4 + fr][fc] = __builtin_amdgcn_mfma_f32_16x16x32_f16(
              a1[fr][kk], b0[fc][kk], acc[4 + fr][fc], 0, 0, 0);
    __builtin_amdgcn_s_setprio(0);
    SCHED0;
    BAR;
    // ---- phase 2: stage A(t+2); counted vmcnt; MFMA a1/a0 x b1 ----
    if (t + 2 < NT) {
      stage(A, ldA, bm, t + 2, sA, 0);
      stage(A, ldA, bm, t + 2, sA, 1);
      VMCNT(4);
    } else {
      VMCNT(0);
    }
    BAR;
    __builtin_amdgcn_s_setprio(1);
#pragma unroll
    for (int fr = 0; fr < 4; fr++)
#pragma unroll
      for (int fc = 0; fc < 2; fc++)
#pragma unroll
        for (int kk = 0; kk < 2; kk++)
          acc[4 + fr][2 + fc] = __builtin_amdgcn_mfma_f32_16x16x32_f16(
              a1[fr][kk], b1[fc][kk], acc[4 + fr][2 + fc], 0, 0, 0);
#pragma unroll
    for (int fr = 0; fr < 4; fr++)
#pragma unroll
      for (int fc = 0; fc < 2; fc++)
#pragma unroll
        for (int kk = 0; kk < 2; kk++)
          acc[fr][2 + fc] = __builtin_amdgcn_mfma_f32_16x16x32_f16(
              a0[fr][kk], b1[fc][kk], acc[fr][2 + fc], 0, 0, 0);
    __builtin_amdgcn_s_setprio(0);
    SCHED0;
    BAR;
  }
  VMCNT(0);

  // epilogue
#pragma unroll
  for (int fr = 0; fr < 8; fr++) {
#pragma unroll
    for (int fc = 0; fc < 4; fc++) {
#pragma unroll
      for (int i = 0; i < 4; i++) {
        const int row = bm + wm * 128 + fr * 16 + (lane >> 4) * 4 + i;
        const int col = bn + wn * 64 + fc * 16 + r0;
        const size_t idx = (size_t)row * N + col;
        const float val = acc[fr][fc][i];
        if constexpr (EPI == 0) {
          outH[idx] = (_Float16)val;
        } else if constexpr (EPI == 1) {
          const float tt = fmaxf(val, 0.f);
          outH[idx] = (_Float16)(tt * tt);
        } else if constexpr (EPI == 2) {
          outH[idx] = (_Float16)(1.f / (1.f + __expf(-val)));
        } else if constexpr (EPI == 3) {
          outF[idx] = res[idx] + val;
        } else {
          outF[idx] = outF[idx] + (float)scale[idx] * val;
        }
      }
    }
  }
}

// ---------------------------------------------------------------------------
extern "C" void kernel_launch(void* const* d_in, const int* in_sizes, int n_in,
                              void* d_out, int out_size, void* d_ws,
                              size_t ws_size, hipStream_t stream) {
  (void)in_sizes; (void)n_in; (void)out_size;
  const float* x_in      = (const float*)d_in[0];
  const float* ln1_g     = (const float*)d_in[1];
  const float* ln1_b     = (const float*)d_in[2];
  const float* ln2_g     = (const float*)d_in[3];
  const float* ln2_b     = (const float*)d_in[4];
  const float* tm_mix_k  = (const float*)d_in[5];
  const float* tm_mix_v  = (const float*)d_in[6];
  const float* tm_mix_r  = (const float*)d_in[7];
  const float* tm_Wk     = (const float*)d_in[8];
  const float* tm_Wv     = (const float*)d_in[9];
  const float* tm_Wr     = (const float*)d_in[10];
  const float* time_decay= (const float*)d_in[11];
  const float* time_first= (const float*)d_in[12];
  const float* Wo        = (const float*)d_in[13];
  const float* cm_mix_k  = (const float*)d_in[14];
  const float* cm_mix_r  = (const float*)d_in[15];
  const float* cm_Wk     = (const float*)d_in[16];
  const float* cm_Wv     = (const float*)d_in[17];
  const float* cm_Wr     = (const float*)d_in[18];
  float* out = (float*)d_out;
  char* ws = (char*)d_ws;
  const size_t MB = 1024ull * 1024ull;

  // ---- workspace layout ----
  _Float16* WkT   = (_Float16*)(ws + 0 * MB);    // 2MB (1024x1024 f16)
  _Float16* WvT   = (_Float16*)(ws + 2 * MB);
  _Float16* WrT   = (_Float16*)(ws + 4 * MB);
  _Float16* WoT   = (_Float16*)(ws + 6 * MB);
  _Float16* cmWkT = (_Float16*)(ws + 8 * MB);    // 8MB (4096x1024)
  _Float16* cmWvT = (_Float16*)(ws + 16 * MB);   // 8MB (1024x4096)
  _Float16* cmWrT = (_Float16*)(ws + 24 * MB);   // 2MB
  // wkv scratch reuses WkT/WvT/WrT slots (dead after k/v/r GEMMs):
  float* aal = (float*)(ws + 0 * MB);            // 1MB each
  float* bbl = (float*)(ws + 1 * MB);
  float* ppl = (float*)(ws + 2 * MB);
  float* aap = (float*)(ws + 3 * MB);
  float* bbp = (float*)(ws + 4 * MB);
  float* ppp = (float*)(ws + 5 * MB);
  // time-mix slots (32MB each):
  _Float16* kbuf  = (_Float16*)(ws + 26 * MB);   // [26,58)
  _Float16* xk    = (_Float16*)(ws + 58 * MB);   // [58,90)
  _Float16* xv    = (_Float16*)(ws + 90 * MB);   // [90,122)
  _Float16* xr    = (_Float16*)(ws + 122 * MB);  // [122,154)
  _Float16* kb    = kbuf;
  _Float16* vb    = xk;                          // xk dead after gemm K
  _Float16* rb    = xv;                          // xv dead after gemm V
  _Float16* ab    = xr;                          // xr dead after gemm R

  const int SMEM = 131072;
  static bool attr_done = false;
  if (!attr_done) {
    hipFuncSetAttribute((const void*)gemm8<0>, hipFuncAttributeMaxDynamicSharedMemorySize, SMEM);
    hipFuncSetAttribute((const void*)gemm8<1>, hipFuncAttributeMaxDynamicSharedMemorySize, SMEM);
    hipFuncSetAttribute((const void*)gemm8<2>, hipFuncAttributeMaxDynamicSharedMemorySize, SMEM);
    hipFuncSetAttribute((const void*)gemm8<3>, hipFuncAttributeMaxDynamicSharedMemorySize, SMEM);
    hipFuncSetAttribute((const void*)gemm8<4>, hipFuncAttributeMaxDynamicSharedMemorySize, SMEM);
    attr_done = true;
  }

  // --- weight prep: all 7 transposes in ONE dispatch ---
  WTTab tab;
  tab.e[0] = {tm_Wk, WkT,   1024, 1024, 256};
  tab.e[1] = {tm_Wv, WvT,   1024, 1024, 256};
  tab.e[2] = {tm_Wr, WrT,   1024, 1024, 256};
  tab.e[3] = {Wo,    WoT,   1024, 1024, 256};
  tab.e[4] = {cm_Wk, cmWkT, 1024, 4096, 1024};
  tab.e[5] = {cm_Wv, cmWvT, 4096, 1024, 1024};
  tab.e[6] = {cm_Wr, cmWrT, 1024, 1024, 256};
  wtrans_all<<<dim3(3328), 256, 0, stream>>>(tab);

  // --- time mixing: fused LN1+mix ---
  lnmix_kernel<true><<<dim3(ROWS / 4), 256, 0, stream>>>(
      x_in, ln1_g, ln1_b, tm_mix_k, tm_mix_v, tm_mix_r, xk, xv, xr);
  gemm8<0><<<dim3(64 * 4), 512, SMEM, stream>>>(xk, 1024, WkT, 1024, 1024, 1024,
                                                4, nullptr, kb, nullptr, nullptr);
  gemm8<0><<<dim3(64 * 4), 512, SMEM, stream>>>(xv, 1024, WvT, 1024, 1024, 1024,
                                                4, nullptr, vb, nullptr, nullptr);
  gemm8<0><<<dim3(64 * 4), 512, SMEM, stream>>>(xr, 1024, WrT, 1024, 1024, 1024,
                                                4, nullptr, rb, nullptr, nullptr);
  wkv_pass1<<<dim3(Bb * CC * Hh / 256), 256, 0, stream>>>(kb, vb, time_decay,
                                                          aal, bbl, ppl);
  wkv_pass2<<<dim3(Bb * Hh / 256), 256, 0, stream>>>(time_decay, aal, bbl, ppl,
                                                     aap, bbp, ppp);
  wkv_pass3<<<dim3(Bb * CC * Hh / 256), 256, 0, stream>>>(
      kb, vb, rb, time_decay, time_first, aap, bbp, ppp, ab);
  gemm8<3><<<dim3(64 * 4), 512, SMEM, stream>>>(ab, 1024, WoT, 1024, 1024, 1024,
                                                4, out, nullptr, x_in, nullptr);

  // --- channel mixing ---
  if (ws_size >= 250ull * MB) {
    // single-pass: kc = 16384x4096 f16 (128MB); one RMW pass over `out`
    _Float16* xk2s = (_Float16*)(ws + 26 * MB);   // [26,58)
    _Float16* rcs  = (_Float16*)(ws + 58 * MB);   // [58,90)
    _Float16* kcs  = (_Float16*)(ws + 90 * MB);   // [90,218)
    _Float16* xr2s = (_Float16*)(ws + 218 * MB);  // [218,250)
    lnmix_kernel<false><<<dim3(ROWS / 4), 256, 0, stream>>>(
        out, ln2_g, ln2_b, cm_mix_k, nullptr, cm_mix_r, xk2s, nullptr, xr2s);
    gemm8<2><<<dim3(64 * 4), 512, SMEM, stream>>>(xr2s, 1024, cmWrT, 1024, 1024,
                                                  1024, 4, nullptr, rcs, nullptr,
                                                  nullptr);
    gemm8<1><<<dim3(64 * 16), 512, SMEM, stream>>>(xk2s, 1024, cmWkT, 1024,
                                                   4096, 1024, 16, nullptr, kcs,
                                                   nullptr, nullptr);
    gemm8<4><<<dim3(64 * 4), 512, SMEM, stream>>>(kcs, 4096, cmWvT, 4096, 1024,
                                                  4096, 4, out, nullptr, nullptr,
                                                  rcs);
  } else {
    // two-half fallback (154MB peak, proven)
    _Float16* xr2   = (_Float16*)(ws + 58 * MB);   // [58,90)
    _Float16* xk2   = (_Float16*)(ws + 90 * MB);   // [90,122)
    _Float16* rc    = (_Float16*)(ws + 122 * MB);  // [122,154)
    _Float16* kc    = (_Float16*)(ws + 26 * MB);   // [26,90) 64MB
    lnmix_kernel<false><<<dim3(ROWS / 4), 256, 0, stream>>>(
        out, ln2_g, ln2_b, cm_mix_k, nullptr, cm_mix_r, xk2, nullptr, xr2);
    gemm8<2><<<dim3(64 * 4), 512, SMEM, stream>>>(xr2, 1024, cmWrT, 1024, 1024,
                                                  1024, 4, nullptr, rc, nullptr,
                                                  nullptr);
    for (int half = 0; half < 2; half++) {
      const _Float16* Bk = cmWkT + (size_t)half * 2048 * 1024;  // N-half rows
      const _Float16* Bv = cmWvT + (size_t)half * 2048;         // K-half cols
      gemm8<1><<<dim3(64 * 8), 512, SMEM, stream>>>(xk2, 1024, Bk, 1024, 2048,
                                                    1024, 8, nullptr, kc,
                                                    nullptr, nullptr);
      gemm8<4><<<dim3(64 * 4), 512, SMEM, stream>>>(kc, 2048, Bv, 4096, 1024,
                                                    2048, 4, out, nullptr,
                                                    nullptr, rc);
    }
  }
}